// Round 9
// baseline (632.031 us; speedup 1.0000x reference)
//
#include <hip/hip_runtime.h>
#include <math.h>

typedef __attribute__((ext_vector_type(8))) short short8;
typedef __attribute__((ext_vector_type(4))) float f32x4;

#define NREC 125

// ---- workspace layout (float offsets) ---- total 742528 floats = 2.97 MB
#define WS_SPART 0          // srr partials [16][8192]           -> 131072
#define WS_GPART 131072     // g partials [512][64]              -> 163840
#define WS_WPART 163840     // wsum partials [512][2]            -> 164864
#define WS_CPART 164864     // colsum partials [5][125*64]       -> 204864
#define WS_T1R   204864
#define WS_T1C   204928
#define WS_AL    204992
#define WS_BE    205056
#define WS_GA    205120
#define WS_DE    205184
#define WS_ECP   205248
#define WS_ECN   205312
#define WS_W     205376     // w vectors [6][64]                 -> 205760
#define WS_MUZ   205760
#define WS_WSUM  205824     // (unused slack, pad 64)
#define WS_SYNC  205888     // 16 uints: cnt[5] @ +0, flag[5] @ +8
#define WS_RNORM 205952     // row norms [8192]                  -> 214144
#define WS_R2H   214144     // th2rr bf16 hi ushort[4096]        -> 216192
#define WS_R2L   216192     //                                   -> 218240
#define WS_FH    218240     // Fr bf16 hi ushort[8192*64]        -> 480384
#define WS_FL    480384     //                                   -> 742528

__device__ __forceinline__ float waveReduceSum(float v) {
#pragma unroll
    for (int m = 32; m >= 1; m >>= 1) v += __shfl_xor(v, m, 64);
    return v;
}
__device__ __forceinline__ unsigned short f2bf(float f) {
    unsigned int u = __float_as_uint(f);
    unsigned int r = (u + 0x7fffu + ((u >> 16) & 1u)) >> 16;
    return (unsigned short)r;
}
__device__ __forceinline__ float bf2f(unsigned short h) {
    return __uint_as_float(((unsigned int)h) << 16);
}
// scoped release store / acquire load: write-through for THESE lines only (no L2 flush)
__device__ __forceinline__ void stG(float* p, float v) {
    __hip_atomic_store(p, v, __ATOMIC_RELEASE, __HIP_MEMORY_SCOPE_AGENT);
}
__device__ __forceinline__ float ldG(const float* p) {
    return __hip_atomic_load(p, __ATOMIC_ACQUIRE, __HIP_MEMORY_SCOPE_AGENT);
}

// K1: blocks 0..511: 16 rows each -> Fh/Fl + rnorm + g/wsum partials.
//     block 512: setup math + th2rr bf16 split + sync-state zeroing.
__global__ __launch_bounds__(256) void k_fr(
    const float* __restrict__ A, const float* __restrict__ b, const float* __restrict__ c,
    const float* __restrict__ th1r, const float* __restrict__ th1c,
    const float* __restrict__ th2rr, const float* __restrict__ th2rc,
    const float* __restrict__ th3rr, const float* __restrict__ th3rc, const float* __restrict__ th3cr,
    const float* __restrict__ th4rr, const float* __restrict__ th4rc, const float* __restrict__ th4cr,
    const int* __restrict__ zp,
    unsigned short* __restrict__ Fh, unsigned short* __restrict__ Fl,
    unsigned short* __restrict__ R2H, unsigned short* __restrict__ R2L,
    float* __restrict__ ws)
{
    int tid = threadIdx.x, lane = tid & 63, wid = tid >> 6;

    if (blockIdx.x == 512) {
        __shared__ float fcraw[64], fz[64], sh4a[64], sh4b[64];
        int p = lane;
        int z = zp[0];
        if (tid < 16) ((unsigned*)(ws + WS_SYNC))[tid] = 0u;
        float cv = (p < 63) ? c[p] : 0.f;
        fcraw[p] = cv;
        float av = (p < 63) ? A[z * 63 + p] : b[z];
        float s2 = waveReduceSum(av * av);
        fz[p] = av * rsqrtf(s2);
        __syncthreads();

        float t1 = 0.f, t2 = 0.f, w0 = 0.f;
#pragma unroll 8
        for (int k = 0; k < 64; k++) {
            t1 += th1r[p * 64 + k] * fz[k];
            t2 += th1c[p * 64 + k] * fz[k];
            w0 += th2rc[p * 64 + k] * fcraw[k];
        }
        ws[WS_T1R + p] = t1;
        ws[WS_T1C + p] = t2;
        ws[WS_W + p] = t1 + w0;               // w for sweep 0

        sh4a[p] = th4rr[p];
        sh4b[p] = th4rc[p];
        __syncthreads();
        float a = 0.f, bb = 0.f, g = 0.f, d = 0.f;
#pragma unroll 8
        for (int k = 0; k < 64; k++) {
            float t4 = sh4a[k];
            a  += th3rr[p * 64 + k] * fmaxf(t4, 0.f);
            bb += th3rr[p * 64 + k] * fmaxf(-t4, 0.f);
            float t5 = sh4b[k];
            g  += th3rc[p * 64 + k] * fmaxf(t5, 0.f);
            d  += th3rc[p * 64 + k] * fmaxf(-t5, 0.f);
        }
        ws[WS_AL + p] = a; ws[WS_BE + p] = bb;
        ws[WS_GA + p] = g; ws[WS_DE + p] = d;
        __syncthreads();
        sh4a[p] = th4cr[p];
        __syncthreads();
        float e1 = 0.f, e2 = 0.f;
#pragma unroll 8
        for (int k = 0; k < 64; k++) {
            float t6 = sh4a[k];
            e1 += th3cr[p * 64 + k] * fmaxf(t6, 0.f);
            e2 += th3cr[p * 64 + k] * fmaxf(-t6, 0.f);
        }
        ws[WS_ECP + p] = e1; ws[WS_ECN + p] = e2;

#pragma unroll
        for (int i = 0; i < 16; i++) {
            int idx = tid * 16 + i;
            float f = th2rr[idx];
            unsigned short h = f2bf(f);
            R2H[idx] = h;
            R2L[idx] = f2bf(f - bf2f(h));
        }
        return;
    }

    __shared__ float gsh[64];
    __shared__ float wsh2[2];
    if (tid < 64) gsh[tid] = 0.f;
    if (tid < 2) wsh2[tid] = 0.f;
    __syncthreads();

    float cv = (lane < 63) ? c[lane] : 0.f;
    float cn2 = waveReduceSum(cv * cv);
    float fcnl = cv * rsqrtf(cn2);

    int r0 = blockIdx.x * 16 + wid * 4;
    float gl = 0.f, lp = 0.f, ln = 0.f;
#pragma unroll
    for (int i = 0; i < 4; i++) {
        int r = r0 + i;
        if (r < 8000) {
            float val = (lane < 63) ? A[r * 63 + lane] : b[r];
            float s2 = waveReduceSum(val * val);
            float f = val * rsqrtf(s2);
            unsigned short h = f2bf(f);
            Fh[r * 64 + lane] = h;
            Fl[r * 64 + lane] = f2bf(f - bf2f(h));
            gl += f;
            float w = waveReduceSum(f * fcnl);
            if (lane == 0) {
                ws[WS_RNORM + r] = sqrtf(s2);
                lp += fmaxf(w, 0.f); ln += fmaxf(-w, 0.f);
            }
        } else {
            Fh[r * 64 + lane] = 0;
            Fl[r * 64 + lane] = 0;
        }
    }
    atomicAdd(&gsh[lane], gl);
    if (lane == 0) { atomicAdd(&wsh2[0], lp); atomicAdd(&wsh2[1], ln); }
    __syncthreads();
    if (tid < 64) ws[WS_GPART + blockIdx.x * 64 + tid] = gsh[tid];
    if (tid == 64) ws[WS_WPART + blockIdx.x * 2 + 0] = wsh2[0];
    if (tid == 65) ws[WS_WPART + blockIdx.x * 2 + 1] = wsh2[1];
}

// K2: MFMA gram row-sums, LDS-staged double-buffered B shared by 4 waves.
// grid (32,16), block 256, 64 v-rows/wave. (round-8 proven version)
__global__ __launch_bounds__(256) void k_gram(
    const unsigned short* __restrict__ Fh, const unsigned short* __restrict__ Fl,
    float* __restrict__ ws)
{
    __shared__ short BshH[2][16 * 72];
    __shared__ short BshL[2][16 * 72];
    int tid = threadIdx.x, lane = tid & 63, wid = tid >> 6;
    int m = lane & 15, quad = lane >> 4;
    int vbase = blockIdx.x * 256 + wid * 64;
    int sr = tid >> 4, sc = (tid & 15) * 4;

    short8 AH[8], AL[8];
#pragma unroll
    for (int pt = 0; pt < 4; pt++)
#pragma unroll
        for (int q = 0; q < 2; q++) {
            int off = (vbase + pt * 16 + m) * 64 + q * 32 + quad * 8;
            AH[pt * 2 + q] = *(const short8*)(Fh + off);
            AL[pt * 2 + q] = *(const short8*)(Fl + off);
        }
    float srr[16];
#pragma unroll
    for (int i = 0; i < 16; i++) srr[i] = 0.f;

    const int y = blockIdx.y;
    {
        int u0 = y * 16;
        *(uint2*)(&BshH[0][sr * 72 + sc]) = *(const uint2*)(Fh + (u0 + sr) * 64 + sc);
        *(uint2*)(&BshL[0][sr * 72 + sc]) = *(const uint2*)(Fl + (u0 + sr) * 64 + sc);
    }
    __syncthreads();

#pragma unroll 1
    for (int k = 0; k < 32; k++) {
        int cur = k & 1;
        uint2 sH, sL;
        if (k < 31) {
            int u0 = (y + 16 * (k + 1)) * 16;
            sH = *(const uint2*)(Fh + (u0 + sr) * 64 + sc);
            sL = *(const uint2*)(Fl + (u0 + sr) * 64 + sc);
        }
        short8 BH[2], BL[2];
#pragma unroll
        for (int q = 0; q < 2; q++) {
            BH[q] = *(const short8*)(&BshH[cur][m * 72 + q * 32 + quad * 8]);
            BL[q] = *(const short8*)(&BshL[cur][m * 72 + q * 32 + quad * 8]);
        }
#pragma unroll
        for (int pt = 0; pt < 4; pt++) {
            f32x4 a = {0.f, 0.f, 0.f, 0.f};
#pragma unroll
            for (int q = 0; q < 2; q++) {
                a = __builtin_amdgcn_mfma_f32_16x16x32_bf16(AH[pt*2+q], BH[q], a, 0, 0, 0);
                a = __builtin_amdgcn_mfma_f32_16x16x32_bf16(AH[pt*2+q], BL[q], a, 0, 0, 0);
                a = __builtin_amdgcn_mfma_f32_16x16x32_bf16(AL[pt*2+q], BH[q], a, 0, 0, 0);
            }
#pragma unroll
            for (int r = 0; r < 4; r++) srr[pt*4+r] += fmaxf(a[r], 0.f);
        }
        if (k < 31) {
            *(uint2*)(&BshH[1 - cur][sr * 72 + sc]) = sH;
            *(uint2*)(&BshL[1 - cur][sr * 72 + sc]) = sL;
            __syncthreads();
        }
    }
#pragma unroll
    for (int pt = 0; pt < 4; pt++)
#pragma unroll
        for (int r = 0; r < 4; r++) {
            float s = srr[pt * 4 + r];
#pragma unroll
            for (int mm = 8; mm >= 1; mm >>= 1) s += __shfl_xor(s, mm, 64);
            if (m == 0)
                ws[WS_SPART + y * 8192 + vbase + pt * 16 + quad * 4 + r] = s;
        }
}

// K3: fused edge-terms + 5 sweeps + head. mu register/LDS-resident; cross-block
// data via scoped release/acquire atomics only (no fences, no L2 flush).
__global__ __launch_bounds__(256) void k_rec(
    const float* __restrict__ c,
    const float* __restrict__ th2cr, const float* __restrict__ th2rc,
    const float* __restrict__ th6r, const float* __restrict__ th6c,
    const float* __restrict__ th7, const float* __restrict__ W8,
    const float* __restrict__ b8, const int* __restrict__ zp,
    float* __restrict__ ws,
    const unsigned short* __restrict__ Fh, const unsigned short* __restrict__ Fl,
    const unsigned short* __restrict__ R2H, const unsigned short* __restrict__ R2L,
    float* __restrict__ out)
{
    __shared__ float XF[64][68];
    __shared__ float red[256], colp[256];
    __shared__ __align__(16) float wS[64], alS[64], beS[64], gaS[64], deS[64];
    __shared__ float fcnS[64], gS[64], t1rS[64], t1cS[64], ecpS[64], ecnS[64];
    __shared__ float Ssh[64], ysh[64], wsh[64], wsumS[2], muzS[64], feat[128];

    int tid = threadIdx.x, lane = tid & 63, wid = tid >> 6;
    int m = lane & 15, quad = lane >> 4;
    int vblk = blockIdx.x * 64;
    int cw = wid * 16 + m;
    int v = vblk + cw;
    int z = zp[0];
    unsigned* syncp = (unsigned*)(ws + WS_SYNC);

    // ---- prologue: coefficients + reductions
    if (wid == 0) {
        float cv = (lane < 63) ? c[lane] : 0.f;
        float cn2 = waveReduceSum(cv * cv);
        fcnS[lane] = cv * rsqrtf(cn2);
        wS[lane] = ws[WS_W + lane];
    } else if (wid == 1) {
        alS[lane] = ws[WS_AL + lane]; beS[lane] = ws[WS_BE + lane];
        t1rS[lane] = ws[WS_T1R + lane];
        float wp = 0.f;
#pragma unroll
        for (int k = 0; k < 8; k++) wp += ws[WS_WPART + (lane + 64 * k) * 2];
        wp = waveReduceSum(wp);
        if (lane == 0) wsumS[0] = wp;
    } else if (wid == 2) {
        gaS[lane] = ws[WS_GA + lane]; deS[lane] = ws[WS_DE + lane];
        t1cS[lane] = ws[WS_T1C + lane];
        float wn = 0.f;
#pragma unroll
        for (int k = 0; k < 8; k++) wn += ws[WS_WPART + (lane + 64 * k) * 2 + 1];
        wn = waveReduceSum(wn);
        if (lane == 0) wsumS[1] = wn;
    } else {
        ecpS[lane] = ws[WS_ECP + lane]; ecnS[lane] = ws[WS_ECN + lane];
    }
    float gv = 0.f;
    for (int bb = 0; bb < 128; bb++) gv += ws[WS_GPART + (wid * 128 + bb) * 64 + lane];
    red[tid] = gv;
    __syncthreads();
    if (tid < 64) gS[tid] = red[tid] + red[64 + tid] + red[128 + tid] + red[192 + tid];
    __syncthreads();

    // ---- per-lane row data: fr slice, e4, initial B-frags
    float x[16];
#pragma unroll
    for (int q = 0; q < 2; q++) {
        short8 h8 = *(const short8*)(Fh + v * 64 + q * 32 + quad * 8);
        short8 l8 = *(const short8*)(Fl + v * 64 + q * 32 + quad * 8);
#pragma unroll
        for (int j = 0; j < 8; j++)
            x[q * 8 + j] = bf2f((unsigned short)h8[j]) + bf2f((unsigned short)l8[j]);
    }
    float dw = 0.f, dg = 0.f;
#pragma unroll
    for (int q = 0; q < 2; q++)
#pragma unroll
        for (int j = 0; j < 8; j++) {
            int k = q * 32 + quad * 8 + j;
            dw += x[q * 8 + j] * fcnS[k];
            dg += x[q * 8 + j] * gS[k];
        }
    dw += __shfl_xor(dw, 16, 64); dw += __shfl_xor(dw, 32, 64);
    dg += __shfl_xor(dg, 16, 64); dg += __shfl_xor(dg, 32, 64);
    float spv = 0.f;
#pragma unroll
    for (int yy = quad * 4; yy < quad * 4 + 4; yy++)
        spv += ws[WS_SPART + yy * 8192 + v];
    spv += __shfl_xor(spv, 16, 64); spv += __shfl_xor(spv, 32, 64);
    float4 e;
    e.x = spv - 1.0f;          // remove diagonal relu(1)
    e.y = spv - dg;            // relu(-x) = relu(x) - x
    e.z = fmaxf(dw, 0.f);
    e.w = fmaxf(-dw, 0.f);

    float rnv = ws[WS_RNORM + v];
    short8 BH[2], BL[2];
#pragma unroll
    for (int q = 0; q < 2; q++) {
        short8 H, L;
#pragma unroll
        for (int j = 0; j < 8; j++) {
            float xm = x[q * 8 + j] * rnv;
            unsigned short h = f2bf(xm);
            H[j] = (short)h;
            L[j] = (short)f2bf(xm - bf2f(h));
        }
        BH[q] = H; BL[q] = L;
    }

    // persistent th2rr A-frags
    short8 RH[8], RL[8];
#pragma unroll
    for (int pt = 0; pt < 4; pt++)
#pragma unroll
        for (int q = 0; q < 2; q++) {
            int off = (pt * 16 + m) * 64 + q * 32 + quad * 8;
            RH[pt * 2 + q] = *(const short8*)(R2H + off);
            RL[pt * 2 + q] = *(const short8*)(R2L + off);
        }
    __syncthreads();

    // ---- sweeps
    for (int t = 0; t < 5; t++) {
#pragma unroll
        for (int pt = 0; pt < 4; pt++) {
            f32x4 a = {0.f, 0.f, 0.f, 0.f};
#pragma unroll
            for (int q = 0; q < 2; q++) {
                a = __builtin_amdgcn_mfma_f32_16x16x32_bf16(RH[pt*2+q], BH[q], a, 0, 0, 0);
                a = __builtin_amdgcn_mfma_f32_16x16x32_bf16(RH[pt*2+q], BL[q], a, 0, 0, 0);
                a = __builtin_amdgcn_mfma_f32_16x16x32_bf16(RL[pt*2+q], BH[q], a, 0, 0, 0);
            }
            int pbase = pt * 16 + quad * 4;
            float4 w4 = *(const float4*)(wS + pbase);
            float4 a4 = *(const float4*)(alS + pbase);
            float4 b4 = *(const float4*)(beS + pbase);
            float4 g4 = *(const float4*)(gaS + pbase);
            float4 d4 = *(const float4*)(deS + pbase);
            float u0 = fmaxf(a[0] + w4.x + a4.x*e.x + b4.x*e.y + g4.x*e.z + d4.x*e.w, 0.f);
            float u1 = fmaxf(a[1] + w4.y + a4.y*e.x + b4.y*e.y + g4.y*e.z + d4.y*e.w, 0.f);
            float u2 = fmaxf(a[2] + w4.z + a4.z*e.x + b4.z*e.y + g4.z*e.z + d4.z*e.w, 0.f);
            float u3 = fmaxf(a[3] + w4.w + a4.w*e.x + b4.w*e.y + g4.w*e.z + d4.w*e.w, 0.f);
            float4 uf; uf.x = u0; uf.y = u1; uf.z = u2; uf.w = u3;
            *(float4*)(&XF[cw][pbase]) = uf;
            float c0 = u0, c1 = u1, c2 = u2, c3 = u3;
#pragma unroll
            for (int mm = 1; mm < 16; mm <<= 1) {
                c0 += __shfl_xor(c0, mm, 64);
                c1 += __shfl_xor(c1, mm, 64);
                c2 += __shfl_xor(c2, mm, 64);
                c3 += __shfl_xor(c3, mm, 64);
            }
            if (m == 0) {
                colp[wid * 64 + pbase + 0] = c0;
                colp[wid * 64 + pbase + 1] = c1;
                colp[wid * 64 + pbase + 2] = c2;
                colp[wid * 64 + pbase + 3] = c3;
            }
            if (t == 4 && v == z) {
                stG(ws + WS_MUZ + pbase + 0, u0);
                stG(ws + WS_MUZ + pbase + 1, u1);
                stG(ws + WS_MUZ + pbase + 2, u2);
                stG(ws + WS_MUZ + pbase + 3, u3);
            }
        }
        __syncthreads();
        if (tid < 64)
            stG(ws + WS_CPART + t * 8000 + blockIdx.x * 64 + tid,
                colp[tid] + colp[64 + tid] + colp[128 + tid] + colp[192 + tid]);
        // rebuild B-frags from the LDS transpose (overlaps the wait)
        if (t < 4) {
#pragma unroll
            for (int q = 0; q < 2; q++) {
                float4 f0 = *(const float4*)(&XF[cw][q * 32 + quad * 8]);
                float4 f1 = *(const float4*)(&XF[cw][q * 32 + quad * 8 + 4]);
                float xv[8] = {f0.x, f0.y, f0.z, f0.w, f1.x, f1.y, f1.z, f1.w};
                short8 H, L;
#pragma unroll
                for (int j = 0; j < 8; j++) {
                    unsigned short h = f2bf(xv[j]);
                    H[j] = (short)h;
                    L[j] = (short)f2bf(xv[j] - bf2f(h));
                }
                BH[q] = H; BL[q] = L;
            }
        }
        __syncthreads();   // drain CPART stores before signalling
        if (tid == 0)
            __hip_atomic_fetch_add(&syncp[t], 1u, __ATOMIC_ACQ_REL, __HIP_MEMORY_SCOPE_AGENT);

        if (blockIdx.x == 0) {
            if (tid == 0) {
                while (__hip_atomic_load(&syncp[t], __ATOMIC_ACQUIRE, __HIP_MEMORY_SCOPE_AGENT) < NREC)
                    __builtin_amdgcn_s_sleep(2);
            }
            __syncthreads();
            float s = 0.f;
            for (int blk = wid; blk < NREC; blk += 4)
                s += ldG(ws + WS_CPART + t * 8000 + blk * 64 + lane);
            red[tid] = s;
            __syncthreads();
            if (tid < 64) Ssh[tid] = red[tid] + red[64 + tid] + red[128 + tid] + red[192 + tid];
            __syncthreads();
            {   // y = relu(t1c + wsum·ec + th2cr @ S)
                int p = wid * 16 + m;
                float acc = 0.f;
                const float4* rowp = (const float4*)(th2cr + p * 64 + quad * 16);
#pragma unroll
                for (int kk = 0; kk < 4; kk++) {
                    float4 r4 = rowp[kk];
                    acc += r4.x * Ssh[quad * 16 + 4 * kk]     + r4.y * Ssh[quad * 16 + 4 * kk + 1]
                         + r4.z * Ssh[quad * 16 + 4 * kk + 2] + r4.w * Ssh[quad * 16 + 4 * kk + 3];
                }
                acc += __shfl_xor(acc, 16, 64);
                acc += __shfl_xor(acc, 32, 64);
                if (quad == 0)
                    ysh[p] = fmaxf(acc + t1cS[p] + wsumS[0] * ecpS[p] + wsumS[1] * ecnS[p], 0.f);
            }
            __syncthreads();
            if (t < 4) {
                {   // w_{t+1} = t1r + th2rc @ y
                    int p = wid * 16 + m;
                    float acc = 0.f;
                    const float4* rowp = (const float4*)(th2rc + p * 64 + quad * 16);
#pragma unroll
                    for (int kk = 0; kk < 4; kk++) {
                        float4 r4 = rowp[kk];
                        acc += r4.x * ysh[quad * 16 + 4 * kk]     + r4.y * ysh[quad * 16 + 4 * kk + 1]
                             + r4.z * ysh[quad * 16 + 4 * kk + 2] + r4.w * ysh[quad * 16 + 4 * kk + 3];
                    }
                    acc += __shfl_xor(acc, 16, 64);
                    acc += __shfl_xor(acc, 32, 64);
                    if (quad == 0) wsh[p] = acc + t1rS[p];
                }
                __syncthreads();
                if (tid < 64) stG(ws + WS_W + (t + 1) * 64 + tid, wsh[tid]);
                __syncthreads();
                if (tid == 0)
                    __hip_atomic_store(&syncp[8 + t], 1u, __ATOMIC_RELEASE, __HIP_MEMORY_SCOPE_AGENT);
            } else {
                // head
                if (tid < 64) muzS[tid] = ldG(ws + WS_MUZ + tid);
                __syncthreads();
                int p = tid;
                if (p < 64) {
                    float t6 = 0.f, t7 = 0.f;
#pragma unroll 8
                    for (int k = 0; k < 64; k++) {
                        t6 += th6r[p * 64 + k] * Ssh[k] + th6c[p * 64 + k] * ysh[k];
                        t7 += th7[p * 64 + k] * muzS[k];
                    }
                    feat[p] = 1.f / (1.f + expf(-t6));
                    feat[64 + p] = 1.f / (1.f + expf(-t7));
                }
                __syncthreads();
                if (p < 2) {
                    float o = b8[p];
                    for (int i = 0; i < 128; i++) o += W8[p * 128 + i] * feat[i];
                    out[p] = o;
                }
            }
        }
        if (t < 4) {
            if (tid == 0) {
                while (__hip_atomic_load(&syncp[8 + t], __ATOMIC_ACQUIRE, __HIP_MEMORY_SCOPE_AGENT) == 0u)
                    __builtin_amdgcn_s_sleep(2);
            }
            __syncthreads();
            if (tid < 64) wS[tid] = ldG(ws + WS_W + (t + 1) * 64 + tid);
            __syncthreads();
        }
    }
}

extern "C" void kernel_launch(void* const* d_in, const int* in_sizes, int n_in,
                              void* d_out, int out_size, void* d_ws, size_t ws_size,
                              hipStream_t stream) {
    (void)in_sizes; (void)n_in; (void)out_size; (void)ws_size;
    const float* A     = (const float*)d_in[0];
    const float* b     = (const float*)d_in[1];
    const float* c     = (const float*)d_in[2];
    const float* th1r  = (const float*)d_in[3];
    const float* th1c  = (const float*)d_in[4];
    const float* th2rr = (const float*)d_in[5];
    const float* th2rc = (const float*)d_in[6];
    const float* th2cr = (const float*)d_in[7];
    const float* th3rr = (const float*)d_in[8];
    const float* th3rc = (const float*)d_in[9];
    const float* th3cr = (const float*)d_in[10];
    const float* th4rr = (const float*)d_in[11];
    const float* th4rc = (const float*)d_in[12];
    const float* th4cr = (const float*)d_in[13];
    const float* th6r  = (const float*)d_in[14];
    const float* th6c  = (const float*)d_in[15];
    const float* th7   = (const float*)d_in[16];
    const float* W8    = (const float*)d_in[17];
    const float* b8    = (const float*)d_in[18];
    const int*   zp    = (const int*)d_in[19];
    float* ws  = (float*)d_ws;
    float* out = (float*)d_out;
    unsigned short* Fh  = (unsigned short*)(ws + WS_FH);
    unsigned short* Fl  = (unsigned short*)(ws + WS_FL);
    unsigned short* R2H = (unsigned short*)(ws + WS_R2H);
    unsigned short* R2L = (unsigned short*)(ws + WS_R2L);

    k_fr<<<513, 256, 0, stream>>>(A, b, c, th1r, th1c, th2rr, th2rc, th3rr, th3rc,
                                  th3cr, th4rr, th4rc, th4cr, zp, Fh, Fl, R2H, R2L, ws);
    k_gram<<<dim3(32, 16), 256, 0, stream>>>(Fh, Fl, ws);
    k_rec<<<NREC, 256, 0, stream>>>(c, th2cr, th2rc, th6r, th6c, th7, W8, b8, zp,
                                    ws, Fh, Fl, R2H, R2L, out);
}

// Round 10
// 285.500 us; speedup vs baseline: 2.2138x; 2.2138x over previous
//
#include <hip/hip_runtime.h>
#include <math.h>

typedef __attribute__((ext_vector_type(8))) short short8;
typedef __attribute__((ext_vector_type(4))) float f32x4;

// ---- workspace layout (float offsets) ---- total 1691968 floats = 6.77 MB
#define WS_SPART 0           // srr partials [128 slots][8192 rows] -> 1048576
#define WS_GPART 1048576     // g partials [512][64]                -> 1081344
#define WS_WPART 1081344     // wsum partials [512][2]              -> 1082368
#define WS_CPART 1082368     // colsum partials [5][125*64]         -> 1122368
#define WS_T1R   1122368
#define WS_T1C   1122432
#define WS_AL    1122496
#define WS_BE    1122560
#define WS_GA    1122624
#define WS_DE    1122688
#define WS_ECP   1122752
#define WS_ECN   1122816
#define WS_W     1122880     // w vectors [6][64]                   -> 1123264
#define WS_MUZ   1123264
#define WS_WSUM  1123328     // reduced wsum_pos/neg (pad 64)
#define WS_RNORM 1123392     // row norms [8192]                    -> 1131584
#define WS_R2H   1131584     // th2rr bf16 hi ushort[4096]          -> 1133632
#define WS_R2L   1133632     //                                     -> 1135680
#define WS_E4    1135680     // (sp,sn,rp,rn)[8000*4]               -> 1167680
#define WS_FH    1167680     // Fr bf16 hi ushort[8192*64]          -> 1429824
#define WS_FL    1429824     //                                     -> 1691968

__device__ __forceinline__ float waveReduceSum(float v) {
#pragma unroll
    for (int m = 32; m >= 1; m >>= 1) v += __shfl_xor(v, m, 64);
    return v;
}
__device__ __forceinline__ unsigned short f2bf(float f) {
    unsigned int u = __float_as_uint(f);
    unsigned int r = (u + 0x7fffu + ((u >> 16) & 1u)) >> 16;
    return (unsigned short)r;
}
__device__ __forceinline__ float bf2f(unsigned short h) {
    return __uint_as_float(((unsigned int)h) << 16);
}

// K1: blocks 0..511: 16 rows each -> Fh/Fl + rnorm + g/wsum partials.
//     block 512: setup math + th2rr bf16 split.
__global__ __launch_bounds__(256) void k_fr(
    const float* __restrict__ A, const float* __restrict__ b, const float* __restrict__ c,
    const float* __restrict__ th1r, const float* __restrict__ th1c,
    const float* __restrict__ th2rr, const float* __restrict__ th2rc,
    const float* __restrict__ th3rr, const float* __restrict__ th3rc, const float* __restrict__ th3cr,
    const float* __restrict__ th4rr, const float* __restrict__ th4rc, const float* __restrict__ th4cr,
    const int* __restrict__ zp,
    unsigned short* __restrict__ Fh, unsigned short* __restrict__ Fl,
    unsigned short* __restrict__ R2H, unsigned short* __restrict__ R2L,
    float* __restrict__ ws)
{
    int tid = threadIdx.x, lane = tid & 63, wid = tid >> 6;

    if (blockIdx.x == 512) {
        __shared__ float fcraw[64], fz[64], sh4a[64], sh4b[64];
        int p = lane;
        int z = zp[0];
        float cv = (p < 63) ? c[p] : 0.f;
        fcraw[p] = cv;
        float av = (p < 63) ? A[z * 63 + p] : b[z];
        float s2 = waveReduceSum(av * av);
        fz[p] = av * rsqrtf(s2);
        __syncthreads();

        float t1 = 0.f, t2 = 0.f, w0 = 0.f;
#pragma unroll 8
        for (int k = 0; k < 64; k++) {
            t1 += th1r[p * 64 + k] * fz[k];
            t2 += th1c[p * 64 + k] * fz[k];
            w0 += th2rc[p * 64 + k] * fcraw[k];
        }
        ws[WS_T1R + p] = t1;
        ws[WS_T1C + p] = t2;
        ws[WS_W + p] = t1 + w0;               // w for sweep 0

        sh4a[p] = th4rr[p];
        sh4b[p] = th4rc[p];
        __syncthreads();
        float a = 0.f, bb = 0.f, g = 0.f, d = 0.f;
#pragma unroll 8
        for (int k = 0; k < 64; k++) {
            float t4 = sh4a[k];
            a  += th3rr[p * 64 + k] * fmaxf(t4, 0.f);
            bb += th3rr[p * 64 + k] * fmaxf(-t4, 0.f);
            float t5 = sh4b[k];
            g  += th3rc[p * 64 + k] * fmaxf(t5, 0.f);
            d  += th3rc[p * 64 + k] * fmaxf(-t5, 0.f);
        }
        ws[WS_AL + p] = a; ws[WS_BE + p] = bb;
        ws[WS_GA + p] = g; ws[WS_DE + p] = d;
        __syncthreads();
        sh4a[p] = th4cr[p];
        __syncthreads();
        float e1 = 0.f, e2 = 0.f;
#pragma unroll 8
        for (int k = 0; k < 64; k++) {
            float t6 = sh4a[k];
            e1 += th3cr[p * 64 + k] * fmaxf(t6, 0.f);
            e2 += th3cr[p * 64 + k] * fmaxf(-t6, 0.f);
        }
        ws[WS_ECP + p] = e1; ws[WS_ECN + p] = e2;

#pragma unroll
        for (int i = 0; i < 16; i++) {
            int idx = tid * 16 + i;
            float f = th2rr[idx];
            unsigned short h = f2bf(f);
            R2H[idx] = h;
            R2L[idx] = f2bf(f - bf2f(h));
        }
        return;
    }

    __shared__ float gsh[64];
    __shared__ float wsh2[2];
    if (tid < 64) gsh[tid] = 0.f;
    if (tid < 2) wsh2[tid] = 0.f;
    __syncthreads();

    float cv = (lane < 63) ? c[lane] : 0.f;
    float cn2 = waveReduceSum(cv * cv);
    float fcnl = cv * rsqrtf(cn2);

    int r0 = blockIdx.x * 16 + wid * 4;
    float gl = 0.f, lp = 0.f, ln = 0.f;
#pragma unroll
    for (int i = 0; i < 4; i++) {
        int r = r0 + i;
        if (r < 8000) {
            float val = (lane < 63) ? A[r * 63 + lane] : b[r];
            float s2 = waveReduceSum(val * val);
            float f = val * rsqrtf(s2);
            unsigned short h = f2bf(f);
            Fh[r * 64 + lane] = h;
            Fl[r * 64 + lane] = f2bf(f - bf2f(h));
            gl += f;
            float w = waveReduceSum(f * fcnl);
            if (lane == 0) {
                ws[WS_RNORM + r] = sqrtf(s2);
                lp += fmaxf(w, 0.f); ln += fmaxf(-w, 0.f);
            }
        } else {
            Fh[r * 64 + lane] = 0;
            Fl[r * 64 + lane] = 0;
        }
    }
    atomicAdd(&gsh[lane], gl);
    if (lane == 0) { atomicAdd(&wsh2[0], lp); atomicAdd(&wsh2[1], ln); }
    __syncthreads();
    if (tid < 64) ws[WS_GPART + blockIdx.x * 64 + tid] = gsh[tid];
    if (tid == 64) ws[WS_WPART + blockIdx.x * 2 + 0] = wsh2[0];
    if (tid == 65) ws[WS_WPART + blockIdx.x * 2 + 1] = wsh2[1];
}

// K2: SYMMETRIC gram: 8256 tile-pair blocks (i<=j over 128 coarse 64-row tiles).
// Each block: full 64x64 gram tile; row-sums -> SPART[j][tile_i rows],
// col-sums (i<j) -> SPART[i][tile_j rows]. Wave w handles A-subtile w (16 rows).
__global__ __launch_bounds__(256) void k_gram(
    const unsigned short* __restrict__ Fh, const unsigned short* __restrict__ Fl,
    float* __restrict__ ws)
{
    __shared__ float rowb[64];
    __shared__ float colb[4][64];
    int tid = threadIdx.x, lane = tid & 63, wid = tid >> 6;
    int m = lane & 15, quad = lane >> 4;

    int bx = blockIdx.x;
    int j = (int)((sqrtf(8.0f * (float)bx + 1.0f) - 1.0f) * 0.5f);
    while ((j + 1) * (j + 2) / 2 <= bx) j++;
    while (j * (j + 1) / 2 > bx) j--;
    int i = bx - j * (j + 1) / 2;             // pair (i, j), i <= j

    // A-frags: this wave's 16 rows of tile i
    short8 AH[2], AL[2];
#pragma unroll
    for (int q = 0; q < 2; q++) {
        int off = (i * 64 + wid * 16 + m) * 64 + q * 32 + quad * 8;
        AH[q] = *(const short8*)(Fh + off);
        AL[q] = *(const short8*)(Fl + off);
    }
    // B-frags: all 64 rows of tile j (4 subtiles) — shared addresses across waves (L1)
    short8 BH[4][2], BL[4][2];
#pragma unroll
    for (int s = 0; s < 4; s++)
#pragma unroll
        for (int q = 0; q < 2; q++) {
            int off = (j * 64 + s * 16 + m) * 64 + q * 32 + quad * 8;
            BH[s][q] = *(const short8*)(Fh + off);
            BL[s][q] = *(const short8*)(Fl + off);
        }

    float rs[4] = {0.f, 0.f, 0.f, 0.f};       // row-sum partial per r (v = quad*4+r)
    float cs[4];                               // col-sum per subtile (u = s*16+m)
#pragma unroll
    for (int s = 0; s < 4; s++) {
        f32x4 a = {0.f, 0.f, 0.f, 0.f};
#pragma unroll
        for (int q = 0; q < 2; q++) {
            a = __builtin_amdgcn_mfma_f32_16x16x32_bf16(AH[q], BH[s][q], a, 0, 0, 0);
            a = __builtin_amdgcn_mfma_f32_16x16x32_bf16(AH[q], BL[s][q], a, 0, 0, 0);
            a = __builtin_amdgcn_mfma_f32_16x16x32_bf16(AL[q], BH[s][q], a, 0, 0, 0);
        }
        float c0 = fmaxf(a[0], 0.f), c1 = fmaxf(a[1], 0.f);
        float c2 = fmaxf(a[2], 0.f), c3 = fmaxf(a[3], 0.f);
        rs[0] += c0; rs[1] += c1; rs[2] += c2; rs[3] += c3;
        cs[s] = c0 + c1 + c2 + c3;            // sum over this lane's 4 v
    }
    // row-sums: reduce over the 16 u lanes (m bits)
#pragma unroll
    for (int r = 0; r < 4; r++) {
        float s = rs[r];
        s += __shfl_xor(s, 1, 64); s += __shfl_xor(s, 2, 64);
        s += __shfl_xor(s, 4, 64); s += __shfl_xor(s, 8, 64);
        if (m == 0) rowb[wid * 16 + quad * 4 + r] = s;
    }
    // col-sums: reduce over quads (v bits), lanes quad==0 hold u = s*16+m
#pragma unroll
    for (int s = 0; s < 4; s++) {
        float v = cs[s];
        v += __shfl_xor(v, 16, 64); v += __shfl_xor(v, 32, 64);
        if (quad == 0) colb[wid][s * 16 + m] = v;
    }
    __syncthreads();
    if (tid < 64) {
        ws[WS_SPART + j * 8192 + i * 64 + tid] = rowb[tid];
        if (i < j)
            ws[WS_SPART + i * 8192 + j * 64 + tid] =
                colb[0][tid] + colb[1][tid] + colb[2][tid] + colb[3][tid];
    }
}

// K3: reduce partials (128 slots); edge terms; in-place mu hi/lo. 125 x 256.
__global__ __launch_bounds__(256) void k_e4(
    const float* __restrict__ c, float* __restrict__ ws,
    unsigned short* __restrict__ MH, unsigned short* __restrict__ ML)
{
    __shared__ float fcnS[64], gS[64], sprow[64], red[256];
    int tid = threadIdx.x, lane = tid & 63, wid = tid >> 6;

    float cv = (lane < 63) ? c[lane] : 0.f;
    float cn2 = waveReduceSum(cv * cv);
    if (wid == 0) fcnS[lane] = cv * rsqrtf(cn2);

    float gv = 0.f;
    for (int bb = 0; bb < 128; bb++) gv += ws[WS_GPART + (wid * 128 + bb) * 64 + lane];
    red[tid] = gv;
    __syncthreads();
    if (tid < 64) gS[tid] = red[tid] + red[64 + tid] + red[128 + tid] + red[192 + tid];
    if (wid == 1) {
        float wp = 0.f;
#pragma unroll
        for (int k = 0; k < 8; k++) wp += ws[WS_WPART + (lane + 64 * k) * 2];
        wp = waveReduceSum(wp);
        if (lane == 0) ws[WS_WSUM] = wp;       // same value from every block
    }
    if (wid == 2) {
        float wn = 0.f;
#pragma unroll
        for (int k = 0; k < 8; k++) wn += ws[WS_WPART + (lane + 64 * k) * 2 + 1];
        wn = waveReduceSum(wn);
        if (lane == 0) ws[WS_WSUM + 1] = wn;
    }
    int v0 = blockIdx.x * 64;
    float sv = 0.f;
    for (int k = wid * 32; k < wid * 32 + 32; k++)
        sv += ws[WS_SPART + k * 8192 + v0 + lane];
    __syncthreads();
    red[tid] = sv;
    __syncthreads();
    if (tid < 64) sprow[tid] = red[tid] + red[64 + tid] + red[128 + tid] + red[192 + tid];
    __syncthreads();

    for (int i2 = 0; i2 < 16; i2++) {
        int i = wid * 16 + i2;
        int v = v0 + i;
        float fr = bf2f(MH[v * 64 + lane]) + bf2f(ML[v * 64 + lane]);
        float dw = waveReduceSum(fr * fcnS[lane]);
        float dg = waveReduceSum(fr * gS[lane]);
        if (lane == 0) {
            float spv = sprow[i];
            float4 e;
            e.x = spv - 1.0f;          // remove diagonal relu(1)
            e.y = spv - dg;            // relu(-x) = relu(x) - x
            e.z = fmaxf(dw, 0.f);
            e.w = fmaxf(-dw, 0.f);
            *(float4*)(ws + WS_E4 + v * 4) = e;
        }
        float x = fr * ws[WS_RNORM + v];
        unsigned short h = f2bf(x);
        MH[v * 64 + lane] = h;
        ML[v * 64 + lane] = f2bf(x - bf2f(h));
    }
}

// K4: pure-parallel mu update for sweep t (w_t precomputed). 125x256.
__global__ __launch_bounds__(256) void k_mu(
    const int* __restrict__ zp, float* __restrict__ ws,
    unsigned short* __restrict__ MH, unsigned short* __restrict__ ML,
    const unsigned short* __restrict__ R2H, const unsigned short* __restrict__ R2L,
    int t)
{
    __shared__ __align__(16) float wS[64], alS[64], beS[64], gaS[64], deS[64];
    __shared__ float colp[256];
    int tid = threadIdx.x, lane = tid & 63, wid = tid >> 6;
    int m = lane & 15, quad = lane >> 4;
    int v = (blockIdx.x * 4 + wid) * 16 + m;   // 125*4*16 = 8000
    int z = zp[0];

    if (wid == 0) wS[lane] = ws[WS_W + t * 64 + lane];
    else if (wid == 1) { alS[lane] = ws[WS_AL + lane]; beS[lane] = ws[WS_BE + lane]; }
    else if (wid == 2) { gaS[lane] = ws[WS_GA + lane]; deS[lane] = ws[WS_DE + lane]; }

    short8 RH[8], RL[8];
#pragma unroll
    for (int pt = 0; pt < 4; pt++)
#pragma unroll
        for (int q = 0; q < 2; q++) {
            int off = (pt * 16 + m) * 64 + q * 32 + quad * 8;
            RH[pt * 2 + q] = *(const short8*)(R2H + off);
            RL[pt * 2 + q] = *(const short8*)(R2L + off);
        }
    short8 BH[2], BL[2];
#pragma unroll
    for (int q = 0; q < 2; q++) {
        BH[q] = *(const short8*)(MH + v * 64 + q * 32 + quad * 8);
        BL[q] = *(const short8*)(ML + v * 64 + q * 32 + quad * 8);
    }
    float4 e = *(const float4*)(ws + WS_E4 + v * 4);
    __syncthreads();

#pragma unroll
    for (int pt = 0; pt < 4; pt++) {
        f32x4 a = {0.f, 0.f, 0.f, 0.f};
#pragma unroll
        for (int q = 0; q < 2; q++) {
            a = __builtin_amdgcn_mfma_f32_16x16x32_bf16(RH[pt*2+q], BH[q], a, 0, 0, 0);
            a = __builtin_amdgcn_mfma_f32_16x16x32_bf16(RH[pt*2+q], BL[q], a, 0, 0, 0);
            a = __builtin_amdgcn_mfma_f32_16x16x32_bf16(RL[pt*2+q], BH[q], a, 0, 0, 0);
        }
        int pbase = pt * 16 + quad * 4;
        float4 w4 = *(const float4*)(wS + pbase);
        float4 a4 = *(const float4*)(alS + pbase);
        float4 b4 = *(const float4*)(beS + pbase);
        float4 g4 = *(const float4*)(gaS + pbase);
        float4 d4 = *(const float4*)(deS + pbase);
        float u0 = fmaxf(a[0] + w4.x + a4.x*e.x + b4.x*e.y + g4.x*e.z + d4.x*e.w, 0.f);
        float u1 = fmaxf(a[1] + w4.y + a4.y*e.x + b4.y*e.y + g4.y*e.z + d4.y*e.w, 0.f);
        float u2 = fmaxf(a[2] + w4.z + a4.z*e.x + b4.z*e.y + g4.z*e.z + d4.z*e.w, 0.f);
        float u3 = fmaxf(a[3] + w4.w + a4.w*e.x + b4.w*e.y + g4.w*e.z + d4.w*e.w, 0.f);
        ushort4 h4, l4;
        h4.x = f2bf(u0); l4.x = f2bf(u0 - bf2f(h4.x));
        h4.y = f2bf(u1); l4.y = f2bf(u1 - bf2f(h4.y));
        h4.z = f2bf(u2); l4.z = f2bf(u2 - bf2f(h4.z));
        h4.w = f2bf(u3); l4.w = f2bf(u3 - bf2f(h4.w));
        *(ushort4*)(MH + v * 64 + pbase) = h4;
        *(ushort4*)(ML + v * 64 + pbase) = l4;
        float c0 = u0, c1 = u1, c2 = u2, c3 = u3;
#pragma unroll
        for (int mm = 1; mm < 16; mm <<= 1) {
            c0 += __shfl_xor(c0, mm, 64);
            c1 += __shfl_xor(c1, mm, 64);
            c2 += __shfl_xor(c2, mm, 64);
            c3 += __shfl_xor(c3, mm, 64);
        }
        if (m == 0) {
            colp[wid * 64 + pbase + 0] = c0;
            colp[wid * 64 + pbase + 1] = c1;
            colp[wid * 64 + pbase + 2] = c2;
            colp[wid * 64 + pbase + 3] = c3;
        }
        if (t == 4 && v == z) {
            float4 o; o.x = u0; o.y = u1; o.z = u2; o.w = u3;
            *(float4*)(ws + WS_MUZ + pbase) = o;
        }
    }
    __syncthreads();
    if (tid < 64)
        ws[WS_CPART + t * 8000 + blockIdx.x * 64 + tid] =
            colp[tid] + colp[64 + tid] + colp[128 + tid] + colp[192 + tid];
}

// K5: column-node update for sweep t -> w_{t+1}; head fused at t=4. 1x256.
__global__ __launch_bounds__(256) void k_colup(
    const float* __restrict__ th2cr, const float* __restrict__ th2rc,
    const float* __restrict__ th6r, const float* __restrict__ th6c,
    const float* __restrict__ th7, const float* __restrict__ W8,
    const float* __restrict__ b8,
    float* __restrict__ ws, float* __restrict__ out, int t)
{
    __shared__ float red[256], Ssh[64], ysh[64], wsh[64], feat[128];
    int tid = threadIdx.x, lane = tid & 63, wid = tid >> 6;
    int m = lane & 15, quad = lane >> 4;

    float s = 0.f;
    for (int blk = wid; blk < 125; blk += 4)
        s += ws[WS_CPART + t * 8000 + blk * 64 + lane];
    red[tid] = s;
    __syncthreads();
    if (tid < 64) Ssh[tid] = red[tid] + red[64 + tid] + red[128 + tid] + red[192 + tid];
    __syncthreads();
    {   // y = relu(t1c + wsum·ec + th2cr @ S), 4-wave split
        int p = wid * 16 + m;
        float acc = 0.f;
        const float4* rowp = (const float4*)(th2cr + p * 64 + quad * 16);
#pragma unroll
        for (int kk = 0; kk < 4; kk++) {
            float4 r4 = rowp[kk];
            acc += r4.x * Ssh[quad * 16 + 4 * kk]     + r4.y * Ssh[quad * 16 + 4 * kk + 1]
                 + r4.z * Ssh[quad * 16 + 4 * kk + 2] + r4.w * Ssh[quad * 16 + 4 * kk + 3];
        }
        acc += __shfl_xor(acc, 16, 64);
        acc += __shfl_xor(acc, 32, 64);
        if (quad == 0)
            ysh[p] = fmaxf(acc + ws[WS_T1C + p] + ws[WS_WSUM] * ws[WS_ECP + p]
                           + ws[WS_WSUM + 1] * ws[WS_ECN + p], 0.f);
    }
    __syncthreads();
    {   // w_{t+1} = t1r + th2rc @ y
        int p = wid * 16 + m;
        float acc = 0.f;
        const float4* rowp = (const float4*)(th2rc + p * 64 + quad * 16);
#pragma unroll
        for (int kk = 0; kk < 4; kk++) {
            float4 r4 = rowp[kk];
            acc += r4.x * ysh[quad * 16 + 4 * kk]     + r4.y * ysh[quad * 16 + 4 * kk + 1]
                 + r4.z * ysh[quad * 16 + 4 * kk + 2] + r4.w * ysh[quad * 16 + 4 * kk + 3];
        }
        acc += __shfl_xor(acc, 16, 64);
        acc += __shfl_xor(acc, 32, 64);
        if (quad == 0) wsh[p] = acc + ws[WS_T1R + p];
    }
    __syncthreads();
    if (tid < 64) ws[WS_W + (t + 1) * 64 + tid] = wsh[tid];

    if (t == 4) {
        int p = tid;
        if (p < 64) {
            float t6 = 0.f, t7 = 0.f;
#pragma unroll 8
            for (int k = 0; k < 64; k++) {
                t6 += th6r[p * 64 + k] * Ssh[k] + th6c[p * 64 + k] * ysh[k];
                t7 += th7[p * 64 + k] * ws[WS_MUZ + k];
            }
            feat[p] = 1.f / (1.f + expf(-t6));
            feat[64 + p] = 1.f / (1.f + expf(-t7));
        }
        __syncthreads();
        if (p < 2) {
            float o = b8[p];
            for (int i = 0; i < 128; i++) o += W8[p * 128 + i] * feat[i];
            out[p] = o;
        }
    }
}

extern "C" void kernel_launch(void* const* d_in, const int* in_sizes, int n_in,
                              void* d_out, int out_size, void* d_ws, size_t ws_size,
                              hipStream_t stream) {
    (void)in_sizes; (void)n_in; (void)out_size; (void)ws_size;
    const float* A     = (const float*)d_in[0];
    const float* b     = (const float*)d_in[1];
    const float* c     = (const float*)d_in[2];
    const float* th1r  = (const float*)d_in[3];
    const float* th1c  = (const float*)d_in[4];
    const float* th2rr = (const float*)d_in[5];
    const float* th2rc = (const float*)d_in[6];
    const float* th2cr = (const float*)d_in[7];
    const float* th3rr = (const float*)d_in[8];
    const float* th3rc = (const float*)d_in[9];
    const float* th3cr = (const float*)d_in[10];
    const float* th4rr = (const float*)d_in[11];
    const float* th4rc = (const float*)d_in[12];
    const float* th4cr = (const float*)d_in[13];
    const float* th6r  = (const float*)d_in[14];
    const float* th6c  = (const float*)d_in[15];
    const float* th7   = (const float*)d_in[16];
    const float* W8    = (const float*)d_in[17];
    const float* b8    = (const float*)d_in[18];
    const int*   zp    = (const int*)d_in[19];
    float* ws  = (float*)d_ws;
    float* out = (float*)d_out;
    unsigned short* Fh  = (unsigned short*)(ws + WS_FH);
    unsigned short* Fl  = (unsigned short*)(ws + WS_FL);
    unsigned short* R2H = (unsigned short*)(ws + WS_R2H);
    unsigned short* R2L = (unsigned short*)(ws + WS_R2L);

    k_fr<<<513, 256, 0, stream>>>(A, b, c, th1r, th1c, th2rr, th2rc, th3rr, th3rc,
                                  th3cr, th4rr, th4rc, th4cr, zp, Fh, Fl, R2H, R2L, ws);
    k_gram<<<8256, 256, 0, stream>>>(Fh, Fl, ws);
    k_e4<<<125, 256, 0, stream>>>(c, ws, Fh, Fl);
    for (int t = 0; t < 5; t++) {
        k_mu<<<125, 256, 0, stream>>>(zp, ws, Fh, Fl, R2H, R2L, t);
        k_colup<<<1, 256, 0, stream>>>(th2cr, th2rc, th6r, th6c, th7, W8, b8, ws, out, t);
    }
}

// Round 11
// 224.323 us; speedup vs baseline: 2.8175x; 1.2727x over previous
//
#include <hip/hip_runtime.h>
#include <math.h>

typedef __attribute__((ext_vector_type(8))) short short8;
typedef __attribute__((ext_vector_type(4))) float f32x4;

// ---- workspace layout (float offsets) ---- total 774464 floats = 3.10 MB
#define WS_SPART 0          // srr partials [16][8192]           -> 131072
#define WS_GPART 131072     // g partials [512][64]              -> 163840
#define WS_WPART 163840     // wsum partials [512][2]            -> 164864
#define WS_CPART 164864     // colsum partials [5][125*64]       -> 204864
#define WS_T1R   204864
#define WS_T1C   204928
#define WS_AL    204992
#define WS_BE    205056
#define WS_GA    205120
#define WS_DE    205184
#define WS_ECP   205248
#define WS_ECN   205312
#define WS_W     205376     // w vectors [6][64]                 -> 205760
#define WS_MUZ   205760
#define WS_WSUM  205824     // reduced wsum_pos/neg (pad 64)
#define WS_RNORM 205888     // row norms [8192]                  -> 214080
#define WS_R2H   214080     // th2rr bf16 hi ushort[4096]        -> 216128
#define WS_R2L   216128     //                                   -> 218176
#define WS_E4    218176     // (sp,sn,rp,rn)[8000*4]             -> 250176
#define WS_FH    250176     // bf16 hi ushort[8192*64] (mu overlays in place)
#define WS_FL    512320     //                                   -> 774464

__device__ __forceinline__ float waveReduceSum(float v) {
#pragma unroll
    for (int m = 32; m >= 1; m >>= 1) v += __shfl_xor(v, m, 64);
    return v;
}
__device__ __forceinline__ unsigned short f2bf(float f) {
    unsigned int u = __float_as_uint(f);
    unsigned int r = (u + 0x7fffu + ((u >> 16) & 1u)) >> 16;
    return (unsigned short)r;
}
__device__ __forceinline__ float bf2f(unsigned short h) {
    return __uint_as_float(((unsigned int)h) << 16);
}

// K1: blocks 0..511: 16 rows each -> Fh/Fl + rnorm + g/wsum partials.
//     block 512: setup math + th2rr bf16 split.
__global__ __launch_bounds__(256) void k_fr(
    const float* __restrict__ A, const float* __restrict__ b, const float* __restrict__ c,
    const float* __restrict__ th1r, const float* __restrict__ th1c,
    const float* __restrict__ th2rr, const float* __restrict__ th2rc,
    const float* __restrict__ th3rr, const float* __restrict__ th3rc, const float* __restrict__ th3cr,
    const float* __restrict__ th4rr, const float* __restrict__ th4rc, const float* __restrict__ th4cr,
    const int* __restrict__ zp,
    unsigned short* __restrict__ Fh, unsigned short* __restrict__ Fl,
    unsigned short* __restrict__ R2H, unsigned short* __restrict__ R2L,
    float* __restrict__ ws)
{
    int tid = threadIdx.x, lane = tid & 63, wid = tid >> 6;

    if (blockIdx.x == 512) {
        __shared__ float fcraw[64], fz[64], sh4a[64], sh4b[64];
        int p = lane;
        int z = zp[0];
        float cv = (p < 63) ? c[p] : 0.f;
        fcraw[p] = cv;
        float av = (p < 63) ? A[z * 63 + p] : b[z];
        float s2 = waveReduceSum(av * av);
        fz[p] = av * rsqrtf(s2);
        __syncthreads();

        float t1 = 0.f, t2 = 0.f, w0 = 0.f;
#pragma unroll 8
        for (int k = 0; k < 64; k++) {
            t1 += th1r[p * 64 + k] * fz[k];
            t2 += th1c[p * 64 + k] * fz[k];
            w0 += th2rc[p * 64 + k] * fcraw[k];
        }
        ws[WS_T1R + p] = t1;
        ws[WS_T1C + p] = t2;
        ws[WS_W + p] = t1 + w0;               // w for sweep 0

        sh4a[p] = th4rr[p];
        sh4b[p] = th4rc[p];
        __syncthreads();
        float a = 0.f, bb = 0.f, g = 0.f, d = 0.f;
#pragma unroll 8
        for (int k = 0; k < 64; k++) {
            float t4 = sh4a[k];
            a  += th3rr[p * 64 + k] * fmaxf(t4, 0.f);
            bb += th3rr[p * 64 + k] * fmaxf(-t4, 0.f);
            float t5 = sh4b[k];
            g  += th3rc[p * 64 + k] * fmaxf(t5, 0.f);
            d  += th3rc[p * 64 + k] * fmaxf(-t5, 0.f);
        }
        ws[WS_AL + p] = a; ws[WS_BE + p] = bb;
        ws[WS_GA + p] = g; ws[WS_DE + p] = d;
        __syncthreads();
        sh4a[p] = th4cr[p];
        __syncthreads();
        float e1 = 0.f, e2 = 0.f;
#pragma unroll 8
        for (int k = 0; k < 64; k++) {
            float t6 = sh4a[k];
            e1 += th3cr[p * 64 + k] * fmaxf(t6, 0.f);
            e2 += th3cr[p * 64 + k] * fmaxf(-t6, 0.f);
        }
        ws[WS_ECP + p] = e1; ws[WS_ECN + p] = e2;

#pragma unroll
        for (int i = 0; i < 16; i++) {
            int idx = tid * 16 + i;
            float f = th2rr[idx];
            unsigned short h = f2bf(f);
            R2H[idx] = h;
            R2L[idx] = f2bf(f - bf2f(h));
        }
        return;
    }

    __shared__ float gsh[64];
    __shared__ float wsh2[2];
    if (tid < 64) gsh[tid] = 0.f;
    if (tid < 2) wsh2[tid] = 0.f;
    __syncthreads();

    float cv = (lane < 63) ? c[lane] : 0.f;
    float cn2 = waveReduceSum(cv * cv);
    float fcnl = cv * rsqrtf(cn2);

    int r0 = blockIdx.x * 16 + wid * 4;
    float gl = 0.f, lp = 0.f, ln = 0.f;
#pragma unroll
    for (int i = 0; i < 4; i++) {
        int r = r0 + i;
        if (r < 8000) {
            float val = (lane < 63) ? A[r * 63 + lane] : b[r];
            float s2 = waveReduceSum(val * val);
            float f = val * rsqrtf(s2);
            unsigned short h = f2bf(f);
            Fh[r * 64 + lane] = h;
            Fl[r * 64 + lane] = f2bf(f - bf2f(h));
            gl += f;
            float w = waveReduceSum(f * fcnl);
            if (lane == 0) {
                ws[WS_RNORM + r] = sqrtf(s2);
                lp += fmaxf(w, 0.f); ln += fmaxf(-w, 0.f);
            }
        } else {
            Fh[r * 64 + lane] = 0;
            Fl[r * 64 + lane] = 0;
        }
    }
    atomicAdd(&gsh[lane], gl);
    if (lane == 0) { atomicAdd(&wsh2[0], lp); atomicAdd(&wsh2[1], ln); }
    __syncthreads();
    if (tid < 64) ws[WS_GPART + blockIdx.x * 64 + tid] = gsh[tid];
    if (tid == 64) ws[WS_WPART + blockIdx.x * 2 + 0] = wsh2[0];
    if (tid == 65) ws[WS_WPART + blockIdx.x * 2 + 1] = wsh2[1];
}

// K2: plain-bf16 MFMA gram (precision via sigmoid saturation; srr rel err ~3e-4).
// grid (32,16), block 256, 64 v-rows/wave. 32-row LDS stages, double-buffered.
__global__ __launch_bounds__(256) void k_gram(
    const unsigned short* __restrict__ Fh, float* __restrict__ ws)
{
    __shared__ short Bsh[2][32 * 72];
    int tid = threadIdx.x, lane = tid & 63, wid = tid >> 6;
    int m = lane & 15, quad = lane >> 4;
    int vbase = blockIdx.x * 256 + wid * 64;
    int srow = tid >> 3;            // 0..31
    int scol = (tid & 7) * 8;       // 0,8,..,56

    short8 AH[8];
#pragma unroll
    for (int pt = 0; pt < 4; pt++)
#pragma unroll
        for (int q = 0; q < 2; q++)
            AH[pt * 2 + q] = *(const short8*)(Fh + (vbase + pt * 16 + m) * 64 + q * 32 + quad * 8);

    float srr[16];
#pragma unroll
    for (int i = 0; i < 16; i++) srr[i] = 0.f;

    const int y = blockIdx.y;       // 32-row chunks c = y + 16k, k=0..15 (256 chunks)
    *(short8*)(&Bsh[0][srow * 72 + scol]) = *(const short8*)(Fh + (y * 32 + srow) * 64 + scol);
    __syncthreads();

#pragma unroll 1
    for (int k = 0; k < 16; k++) {
        int cur = k & 1;
        short8 pre;
        if (k < 15) {
            int cch = y + 16 * (k + 1);
            pre = *(const short8*)(Fh + (cch * 32 + srow) * 64 + scol);
        }
#pragma unroll
        for (int s = 0; s < 2; s++) {
            short8 BH[2];
#pragma unroll
            for (int q = 0; q < 2; q++)
                BH[q] = *(const short8*)(&Bsh[cur][(s * 16 + m) * 72 + q * 32 + quad * 8]);
#pragma unroll
            for (int pt = 0; pt < 4; pt++) {
                f32x4 a = {0.f, 0.f, 0.f, 0.f};
                a = __builtin_amdgcn_mfma_f32_16x16x32_bf16(AH[pt * 2 + 0], BH[0], a, 0, 0, 0);
                a = __builtin_amdgcn_mfma_f32_16x16x32_bf16(AH[pt * 2 + 1], BH[1], a, 0, 0, 0);
#pragma unroll
                for (int r = 0; r < 4; r++) srr[pt * 4 + r] += fmaxf(a[r], 0.f);
            }
        }
        if (k < 15) {
            *(short8*)(&Bsh[1 - cur][srow * 72 + scol]) = pre;
            __syncthreads();
        }
    }
#pragma unroll
    for (int pt = 0; pt < 4; pt++)
#pragma unroll
        for (int r = 0; r < 4; r++) {
            float s = srr[pt * 4 + r];
            s += __shfl_xor(s, 1, 64); s += __shfl_xor(s, 2, 64);
            s += __shfl_xor(s, 4, 64); s += __shfl_xor(s, 8, 64);
            if (m == 0)
                ws[WS_SPART + y * 8192 + vbase + pt * 16 + quad * 4 + r] = s;
        }
}

// K3: FUSED e4 + sweep-0 mu update. 125x256. Computes edge terms (stored for
// later sweeps), mu0 in LDS, MFMA update, writes MH/ML + CPART[0].
__global__ __launch_bounds__(256) void k_mu0(
    const float* __restrict__ c, float* __restrict__ ws,
    unsigned short* __restrict__ MH, unsigned short* __restrict__ ML,
    const unsigned short* __restrict__ R2H, const unsigned short* __restrict__ R2L)
{
    __shared__ float XF[64][68];
    __shared__ float red[256], colp[256];
    __shared__ __align__(16) float wS[64], alS[64], beS[64], gaS[64], deS[64];
    __shared__ float fcnS[64], gS[64], sprow[64];
    __shared__ __align__(16) float e4sh[256];
    int tid = threadIdx.x, lane = tid & 63, wid = tid >> 6;
    int m = lane & 15, quad = lane >> 4;
    int v0 = blockIdx.x * 64;
    int cw = wid * 16 + m;
    int v = v0 + cw;

    if (wid == 0) {
        float cv = (lane < 63) ? c[lane] : 0.f;
        float cn2 = waveReduceSum(cv * cv);
        fcnS[lane] = cv * rsqrtf(cn2);
        wS[lane] = ws[WS_W + lane];
    } else if (wid == 1) {
        alS[lane] = ws[WS_AL + lane]; beS[lane] = ws[WS_BE + lane];
        float wp = 0.f;
#pragma unroll
        for (int k = 0; k < 8; k++) wp += ws[WS_WPART + (lane + 64 * k) * 2];
        wp = waveReduceSum(wp);
        if (lane == 0) ws[WS_WSUM] = wp;       // same value from every block
    } else if (wid == 2) {
        gaS[lane] = ws[WS_GA + lane]; deS[lane] = ws[WS_DE + lane];
        float wn = 0.f;
#pragma unroll
        for (int k = 0; k < 8; k++) wn += ws[WS_WPART + (lane + 64 * k) * 2 + 1];
        wn = waveReduceSum(wn);
        if (lane == 0) ws[WS_WSUM + 1] = wn;
    }
    float gv = 0.f;
#pragma unroll 8
    for (int bb = 0; bb < 128; bb++) gv += ws[WS_GPART + (wid * 128 + bb) * 64 + lane];
    red[tid] = gv;
    __syncthreads();
    if (tid < 64) gS[tid] = red[tid] + red[64 + tid] + red[128 + tid] + red[192 + tid];
    __syncthreads();
    float sv = 0.f;
#pragma unroll
    for (int y = wid * 4; y < wid * 4 + 4; y++) sv += ws[WS_SPART + y * 8192 + v0 + lane];
    red[tid] = sv;
    __syncthreads();
    if (tid < 64) sprow[tid] = red[tid] + red[64 + tid] + red[128 + tid] + red[192 + tid];
    __syncthreads();

    // edge terms + mu0 rows into LDS (wave owns rows wid*16..+15; lane = k)
    for (int i2 = 0; i2 < 16; i2++) {
        int i = wid * 16 + i2;
        int vr = v0 + i;
        float fr = bf2f(MH[vr * 64 + lane]) + bf2f(ML[vr * 64 + lane]);
        float dw = waveReduceSum(fr * fcnS[lane]);
        float dg = waveReduceSum(fr * gS[lane]);
        if (lane == 0) {
            float spv = sprow[i];
            float4 e;
            e.x = spv - 1.0f;          // remove diagonal relu(1)
            e.y = spv - dg;            // relu(-x) = relu(x) - x
            e.z = fmaxf(dw, 0.f);
            e.w = fmaxf(-dw, 0.f);
            *(float4*)(&e4sh[i * 4]) = e;
            *(float4*)(ws + WS_E4 + vr * 4) = e;   // for sweeps 1..4
        }
        XF[i][lane] = fr * ws[WS_RNORM + vr];       // mu0 row (fp32)
    }

    short8 RH[8], RL[8];
#pragma unroll
    for (int pt = 0; pt < 4; pt++)
#pragma unroll
        for (int q = 0; q < 2; q++) {
            int off = (pt * 16 + m) * 64 + q * 32 + quad * 8;
            RH[pt * 2 + q] = *(const short8*)(R2H + off);
            RL[pt * 2 + q] = *(const short8*)(R2L + off);
        }
    __syncthreads();

    // B-frags from XF (hi/lo split of this wave's 16 columns)
    short8 BH[2], BL[2];
#pragma unroll
    for (int q = 0; q < 2; q++) {
        float4 f0 = *(const float4*)(&XF[cw][q * 32 + quad * 8]);
        float4 f1 = *(const float4*)(&XF[cw][q * 32 + quad * 8 + 4]);
        float xv[8] = {f0.x, f0.y, f0.z, f0.w, f1.x, f1.y, f1.z, f1.w};
        short8 H, L;
#pragma unroll
        for (int j = 0; j < 8; j++) {
            unsigned short h = f2bf(xv[j]);
            H[j] = (short)h;
            L[j] = (short)f2bf(xv[j] - bf2f(h));
        }
        BH[q] = H; BL[q] = L;
    }
    float4 e = *(const float4*)(&e4sh[cw * 4]);

#pragma unroll
    for (int pt = 0; pt < 4; pt++) {
        f32x4 a = {0.f, 0.f, 0.f, 0.f};
#pragma unroll
        for (int q = 0; q < 2; q++) {
            a = __builtin_amdgcn_mfma_f32_16x16x32_bf16(RH[pt*2+q], BH[q], a, 0, 0, 0);
            a = __builtin_amdgcn_mfma_f32_16x16x32_bf16(RH[pt*2+q], BL[q], a, 0, 0, 0);
            a = __builtin_amdgcn_mfma_f32_16x16x32_bf16(RL[pt*2+q], BH[q], a, 0, 0, 0);
        }
        int pbase = pt * 16 + quad * 4;
        float4 w4 = *(const float4*)(wS + pbase);
        float4 a4 = *(const float4*)(alS + pbase);
        float4 b4 = *(const float4*)(beS + pbase);
        float4 g4 = *(const float4*)(gaS + pbase);
        float4 d4 = *(const float4*)(deS + pbase);
        float u0 = fmaxf(a[0] + w4.x + a4.x*e.x + b4.x*e.y + g4.x*e.z + d4.x*e.w, 0.f);
        float u1 = fmaxf(a[1] + w4.y + a4.y*e.x + b4.y*e.y + g4.y*e.z + d4.y*e.w, 0.f);
        float u2 = fmaxf(a[2] + w4.z + a4.z*e.x + b4.z*e.y + g4.z*e.z + d4.z*e.w, 0.f);
        float u3 = fmaxf(a[3] + w4.w + a4.w*e.x + b4.w*e.y + g4.w*e.z + d4.w*e.w, 0.f);
        ushort4 h4, l4;
        h4.x = f2bf(u0); l4.x = f2bf(u0 - bf2f(h4.x));
        h4.y = f2bf(u1); l4.y = f2bf(u1 - bf2f(h4.y));
        h4.z = f2bf(u2); l4.z = f2bf(u2 - bf2f(h4.z));
        h4.w = f2bf(u3); l4.w = f2bf(u3 - bf2f(h4.w));
        *(ushort4*)(MH + v * 64 + pbase) = h4;
        *(ushort4*)(ML + v * 64 + pbase) = l4;
        float c0 = u0, c1 = u1, c2 = u2, c3 = u3;
#pragma unroll
        for (int mm = 1; mm < 16; mm <<= 1) {
            c0 += __shfl_xor(c0, mm, 64);
            c1 += __shfl_xor(c1, mm, 64);
            c2 += __shfl_xor(c2, mm, 64);
            c3 += __shfl_xor(c3, mm, 64);
        }
        if (m == 0) {
            colp[wid * 64 + pbase + 0] = c0;
            colp[wid * 64 + pbase + 1] = c1;
            colp[wid * 64 + pbase + 2] = c2;
            colp[wid * 64 + pbase + 3] = c3;
        }
    }
    __syncthreads();
    if (tid < 64)
        ws[WS_CPART + blockIdx.x * 64 + tid] =
            colp[tid] + colp[64 + tid] + colp[128 + tid] + colp[192 + tid];
}

// K4: pure-parallel mu update for sweep t>=1 (w_t precomputed). 125x256.
__global__ __launch_bounds__(256) void k_mu(
    const int* __restrict__ zp, float* __restrict__ ws,
    unsigned short* __restrict__ MH, unsigned short* __restrict__ ML,
    const unsigned short* __restrict__ R2H, const unsigned short* __restrict__ R2L,
    int t)
{
    __shared__ __align__(16) float wS[64], alS[64], beS[64], gaS[64], deS[64];
    __shared__ float colp[256];
    int tid = threadIdx.x, lane = tid & 63, wid = tid >> 6;
    int m = lane & 15, quad = lane >> 4;
    int v = (blockIdx.x * 4 + wid) * 16 + m;   // 125*4*16 = 8000
    int z = zp[0];

    if (wid == 0) wS[lane] = ws[WS_W + t * 64 + lane];
    else if (wid == 1) { alS[lane] = ws[WS_AL + lane]; beS[lane] = ws[WS_BE + lane]; }
    else if (wid == 2) { gaS[lane] = ws[WS_GA + lane]; deS[lane] = ws[WS_DE + lane]; }

    short8 RH[8], RL[8];
#pragma unroll
    for (int pt = 0; pt < 4; pt++)
#pragma unroll
        for (int q = 0; q < 2; q++) {
            int off = (pt * 16 + m) * 64 + q * 32 + quad * 8;
            RH[pt * 2 + q] = *(const short8*)(R2H + off);
            RL[pt * 2 + q] = *(const short8*)(R2L + off);
        }
    short8 BH[2], BL[2];
#pragma unroll
    for (int q = 0; q < 2; q++) {
        BH[q] = *(const short8*)(MH + v * 64 + q * 32 + quad * 8);
        BL[q] = *(const short8*)(ML + v * 64 + q * 32 + quad * 8);
    }
    float4 e = *(const float4*)(ws + WS_E4 + v * 4);
    __syncthreads();

#pragma unroll
    for (int pt = 0; pt < 4; pt++) {
        f32x4 a = {0.f, 0.f, 0.f, 0.f};
#pragma unroll
        for (int q = 0; q < 2; q++) {
            a = __builtin_amdgcn_mfma_f32_16x16x32_bf16(RH[pt*2+q], BH[q], a, 0, 0, 0);
            a = __builtin_amdgcn_mfma_f32_16x16x32_bf16(RH[pt*2+q], BL[q], a, 0, 0, 0);
            a = __builtin_amdgcn_mfma_f32_16x16x32_bf16(RL[pt*2+q], BH[q], a, 0, 0, 0);
        }
        int pbase = pt * 16 + quad * 4;
        float4 w4 = *(const float4*)(wS + pbase);
        float4 a4 = *(const float4*)(alS + pbase);
        float4 b4 = *(const float4*)(beS + pbase);
        float4 g4 = *(const float4*)(gaS + pbase);
        float4 d4 = *(const float4*)(deS + pbase);
        float u0 = fmaxf(a[0] + w4.x + a4.x*e.x + b4.x*e.y + g4.x*e.z + d4.x*e.w, 0.f);
        float u1 = fmaxf(a[1] + w4.y + a4.y*e.x + b4.y*e.y + g4.y*e.z + d4.y*e.w, 0.f);
        float u2 = fmaxf(a[2] + w4.z + a4.z*e.x + b4.z*e.y + g4.z*e.z + d4.z*e.w, 0.f);
        float u3 = fmaxf(a[3] + w4.w + a4.w*e.x + b4.w*e.y + g4.w*e.z + d4.w*e.w, 0.f);
        ushort4 h4, l4;
        h4.x = f2bf(u0); l4.x = f2bf(u0 - bf2f(h4.x));
        h4.y = f2bf(u1); l4.y = f2bf(u1 - bf2f(h4.y));
        h4.z = f2bf(u2); l4.z = f2bf(u2 - bf2f(h4.z));
        h4.w = f2bf(u3); l4.w = f2bf(u3 - bf2f(h4.w));
        *(ushort4*)(MH + v * 64 + pbase) = h4;
        *(ushort4*)(ML + v * 64 + pbase) = l4;
        float c0 = u0, c1 = u1, c2 = u2, c3 = u3;
#pragma unroll
        for (int mm = 1; mm < 16; mm <<= 1) {
            c0 += __shfl_xor(c0, mm, 64);
            c1 += __shfl_xor(c1, mm, 64);
            c2 += __shfl_xor(c2, mm, 64);
            c3 += __shfl_xor(c3, mm, 64);
        }
        if (m == 0) {
            colp[wid * 64 + pbase + 0] = c0;
            colp[wid * 64 + pbase + 1] = c1;
            colp[wid * 64 + pbase + 2] = c2;
            colp[wid * 64 + pbase + 3] = c3;
        }
        if (t == 4 && v == z) {
            float4 o; o.x = u0; o.y = u1; o.z = u2; o.w = u3;
            *(float4*)(ws + WS_MUZ + pbase) = o;
        }
    }
    __syncthreads();
    if (tid < 64)
        ws[WS_CPART + t * 8000 + blockIdx.x * 64 + tid] =
            colp[tid] + colp[64 + tid] + colp[128 + tid] + colp[192 + tid];
}

// K5: column-node update for sweep t -> w_{t+1}; head fused at t=4. 1x256.
__global__ __launch_bounds__(256) void k_colup(
    const float* __restrict__ th2cr, const float* __restrict__ th2rc,
    const float* __restrict__ th6r, const float* __restrict__ th6c,
    const float* __restrict__ th7, const float* __restrict__ W8,
    const float* __restrict__ b8,
    float* __restrict__ ws, float* __restrict__ out, int t)
{
    __shared__ float red[256], Ssh[64], ysh[64], wsh[64], feat[128];
    int tid = threadIdx.x, lane = tid & 63, wid = tid >> 6;
    int m = lane & 15, quad = lane >> 4;

    float s = 0.f;
    for (int blk = wid; blk < 125; blk += 4)
        s += ws[WS_CPART + t * 8000 + blk * 64 + lane];
    red[tid] = s;
    __syncthreads();
    if (tid < 64) Ssh[tid] = red[tid] + red[64 + tid] + red[128 + tid] + red[192 + tid];
    __syncthreads();
    {   // y = relu(t1c + wsum·ec + th2cr @ S), 4-wave split
        int p = wid * 16 + m;
        float acc = 0.f;
        const float4* rowp = (const float4*)(th2cr + p * 64 + quad * 16);
#pragma unroll
        for (int kk = 0; kk < 4; kk++) {
            float4 r4 = rowp[kk];
            acc += r4.x * Ssh[quad * 16 + 4 * kk]     + r4.y * Ssh[quad * 16 + 4 * kk + 1]
                 + r4.z * Ssh[quad * 16 + 4 * kk + 2] + r4.w * Ssh[quad * 16 + 4 * kk + 3];
        }
        acc += __shfl_xor(acc, 16, 64);
        acc += __shfl_xor(acc, 32, 64);
        if (quad == 0)
            ysh[p] = fmaxf(acc + ws[WS_T1C + p] + ws[WS_WSUM] * ws[WS_ECP + p]
                           + ws[WS_WSUM + 1] * ws[WS_ECN + p], 0.f);
    }
    __syncthreads();
    {   // w_{t+1} = t1r + th2rc @ y
        int p = wid * 16 + m;
        float acc = 0.f;
        const float4* rowp = (const float4*)(th2rc + p * 64 + quad * 16);
#pragma unroll
        for (int kk = 0; kk < 4; kk++) {
            float4 r4 = rowp[kk];
            acc += r4.x * ysh[quad * 16 + 4 * kk]     + r4.y * ysh[quad * 16 + 4 * kk + 1]
                 + r4.z * ysh[quad * 16 + 4 * kk + 2] + r4.w * ysh[quad * 16 + 4 * kk + 3];
        }
        acc += __shfl_xor(acc, 16, 64);
        acc += __shfl_xor(acc, 32, 64);
        if (quad == 0) wsh[p] = acc + ws[WS_T1R + p];
    }
    __syncthreads();
    if (tid < 64) ws[WS_W + (t + 1) * 64 + tid] = wsh[tid];

    if (t == 4) {
        int p = tid;
        if (p < 64) {
            float t6 = 0.f, t7 = 0.f;
#pragma unroll 8
            for (int k = 0; k < 64; k++) {
                t6 += th6r[p * 64 + k] * Ssh[k] + th6c[p * 64 + k] * ysh[k];
                t7 += th7[p * 64 + k] * ws[WS_MUZ + k];
            }
            feat[p] = 1.f / (1.f + expf(-t6));
            feat[64 + p] = 1.f / (1.f + expf(-t7));
        }
        __syncthreads();
        if (p < 2) {
            float o = b8[p];
            for (int i = 0; i < 128; i++) o += W8[p * 128 + i] * feat[i];
            out[p] = o;
        }
    }
}

extern "C" void kernel_launch(void* const* d_in, const int* in_sizes, int n_in,
                              void* d_out, int out_size, void* d_ws, size_t ws_size,
                              hipStream_t stream) {
    (void)in_sizes; (void)n_in; (void)out_size; (void)ws_size;
    const float* A     = (const float*)d_in[0];
    const float* b     = (const float*)d_in[1];
    const float* c     = (const float*)d_in[2];
    const float* th1r  = (const float*)d_in[3];
    const float* th1c  = (const float*)d_in[4];
    const float* th2rr = (const float*)d_in[5];
    const float* th2rc = (const float*)d_in[6];
    const float* th2cr = (const float*)d_in[7];
    const float* th3rr = (const float*)d_in[8];
    const float* th3rc = (const float*)d_in[9];
    const float* th3cr = (const float*)d_in[10];
    const float* th4rr = (const float*)d_in[11];
    const float* th4rc = (const float*)d_in[12];
    const float* th4cr = (const float*)d_in[13];
    const float* th6r  = (const float*)d_in[14];
    const float* th6c  = (const float*)d_in[15];
    const float* th7   = (const float*)d_in[16];
    const float* W8    = (const float*)d_in[17];
    const float* b8    = (const float*)d_in[18];
    const int*   zp    = (const int*)d_in[19];
    float* ws  = (float*)d_ws;
    float* out = (float*)d_out;
    unsigned short* Fh  = (unsigned short*)(ws + WS_FH);
    unsigned short* Fl  = (unsigned short*)(ws + WS_FL);
    unsigned short* R2H = (unsigned short*)(ws + WS_R2H);
    unsigned short* R2L = (unsigned short*)(ws + WS_R2L);

    k_fr<<<513, 256, 0, stream>>>(A, b, c, th1r, th1c, th2rr, th2rc, th3rr, th3rc,
                                  th3cr, th4rr, th4rc, th4cr, zp, Fh, Fl, R2H, R2L, ws);
    k_gram<<<dim3(32, 16), 256, 0, stream>>>(Fh, ws);
    k_mu0<<<125, 256, 0, stream>>>(c, ws, Fh, Fl, R2H, R2L);
    for (int t = 0; t < 5; t++) {
        k_colup<<<1, 256, 0, stream>>>(th2cr, th2rc, th6r, th6c, th7, W8, b8, ws, out, t);
        if (t < 4)
            k_mu<<<125, 256, 0, stream>>>(zp, ws, Fh, Fl, R2H, R2L, t + 1);
    }
}

// Round 12
// 223.897 us; speedup vs baseline: 2.8229x; 1.0019x over previous
//
#include <hip/hip_runtime.h>
#include <math.h>

typedef __attribute__((ext_vector_type(8))) short short8;
typedef __attribute__((ext_vector_type(4))) float f32x4;

// ---- workspace layout (float offsets) ---- total 905216 floats = 3.62 MB
#define WS_SPART 0          // srr partials [32][8192]           -> 262144
#define WS_GPART 262144     // g partials [512][64]              -> 294912
#define WS_WPART 294912     // wsum partials [512][2]            -> 295936
#define WS_CPART 295936     // colsum partials [5][125*64]       -> 335936
#define WS_T1R   335936
#define WS_T1C   336000
#define WS_AL    336064
#define WS_BE    336128
#define WS_GA    336192
#define WS_DE    336256
#define WS_ECP   336320
#define WS_ECN   336384
#define WS_W     336448     // w for sweep 0 only
#define WS_MUZ   336512
#define WS_WSUM  336576     // reduced wsum_pos/neg (pad 64)
#define WS_RNORM 336640     // row norms [8192]                  -> 344832
#define WS_R2H   344832     // th2rr bf16 hi ushort[4096]        -> 346880
#define WS_R2L   346880     //                                   -> 348928
#define WS_E4    348928     // (sp,sn,rp,rn)[8000*4]             -> 380928
#define WS_FH    380928     // bf16 hi ushort[8192*64] (mu overlays in place)
#define WS_FL    643072     //                                   -> 905216

__device__ __forceinline__ float waveReduceSum(float v) {
#pragma unroll
    for (int m = 32; m >= 1; m >>= 1) v += __shfl_xor(v, m, 64);
    return v;
}
__device__ __forceinline__ unsigned short f2bf(float f) {
    unsigned int u = __float_as_uint(f);
    unsigned int r = (u + 0x7fffu + ((u >> 16) & 1u)) >> 16;
    return (unsigned short)r;
}
__device__ __forceinline__ float bf2f(unsigned short h) {
    return __uint_as_float(((unsigned int)h) << 16);
}

// K1: blocks 0..511: 16 rows each -> Fh/Fl + rnorm + g/wsum partials.
//     block 512: setup math + th2rr bf16 split.
__global__ __launch_bounds__(256) void k_fr(
    const float* __restrict__ A, const float* __restrict__ b, const float* __restrict__ c,
    const float* __restrict__ th1r, const float* __restrict__ th1c,
    const float* __restrict__ th2rr, const float* __restrict__ th2rc,
    const float* __restrict__ th3rr, const float* __restrict__ th3rc, const float* __restrict__ th3cr,
    const float* __restrict__ th4rr, const float* __restrict__ th4rc, const float* __restrict__ th4cr,
    const int* __restrict__ zp,
    unsigned short* __restrict__ Fh, unsigned short* __restrict__ Fl,
    unsigned short* __restrict__ R2H, unsigned short* __restrict__ R2L,
    float* __restrict__ ws)
{
    int tid = threadIdx.x, lane = tid & 63, wid = tid >> 6;

    if (blockIdx.x == 512) {
        __shared__ float fcraw[64], fz[64], sh4a[64], sh4b[64];
        int p = lane;
        int z = zp[0];
        float cv = (p < 63) ? c[p] : 0.f;
        fcraw[p] = cv;
        float av = (p < 63) ? A[z * 63 + p] : b[z];
        float s2 = waveReduceSum(av * av);
        fz[p] = av * rsqrtf(s2);
        __syncthreads();

        float t1 = 0.f, t2 = 0.f, w0 = 0.f;
#pragma unroll 8
        for (int k = 0; k < 64; k++) {
            t1 += th1r[p * 64 + k] * fz[k];
            t2 += th1c[p * 64 + k] * fz[k];
            w0 += th2rc[p * 64 + k] * fcraw[k];
        }
        ws[WS_T1R + p] = t1;
        ws[WS_T1C + p] = t2;
        ws[WS_W + p] = t1 + w0;               // w for sweep 0

        sh4a[p] = th4rr[p];
        sh4b[p] = th4rc[p];
        __syncthreads();
        float a = 0.f, bb = 0.f, g = 0.f, d = 0.f;
#pragma unroll 8
        for (int k = 0; k < 64; k++) {
            float t4 = sh4a[k];
            a  += th3rr[p * 64 + k] * fmaxf(t4, 0.f);
            bb += th3rr[p * 64 + k] * fmaxf(-t4, 0.f);
            float t5 = sh4b[k];
            g  += th3rc[p * 64 + k] * fmaxf(t5, 0.f);
            d  += th3rc[p * 64 + k] * fmaxf(-t5, 0.f);
        }
        ws[WS_AL + p] = a; ws[WS_BE + p] = bb;
        ws[WS_GA + p] = g; ws[WS_DE + p] = d;
        __syncthreads();
        sh4a[p] = th4cr[p];
        __syncthreads();
        float e1 = 0.f, e2 = 0.f;
#pragma unroll 8
        for (int k = 0; k < 64; k++) {
            float t6 = sh4a[k];
            e1 += th3cr[p * 64 + k] * fmaxf(t6, 0.f);
            e2 += th3cr[p * 64 + k] * fmaxf(-t6, 0.f);
        }
        ws[WS_ECP + p] = e1; ws[WS_ECN + p] = e2;

#pragma unroll
        for (int i = 0; i < 16; i++) {
            int idx = tid * 16 + i;
            float f = th2rr[idx];
            unsigned short h = f2bf(f);
            R2H[idx] = h;
            R2L[idx] = f2bf(f - bf2f(h));
        }
        return;
    }

    __shared__ float gsh[64];
    __shared__ float wsh2[2];
    if (tid < 64) gsh[tid] = 0.f;
    if (tid < 2) wsh2[tid] = 0.f;
    __syncthreads();

    float cv = (lane < 63) ? c[lane] : 0.f;
    float cn2 = waveReduceSum(cv * cv);
    float fcnl = cv * rsqrtf(cn2);

    int r0 = blockIdx.x * 16 + wid * 4;
    float gl = 0.f, lp = 0.f, ln = 0.f;
#pragma unroll
    for (int i = 0; i < 4; i++) {
        int r = r0 + i;
        if (r < 8000) {
            float val = (lane < 63) ? A[r * 63 + lane] : b[r];
            float s2 = waveReduceSum(val * val);
            float f = val * rsqrtf(s2);
            unsigned short h = f2bf(f);
            Fh[r * 64 + lane] = h;
            Fl[r * 64 + lane] = f2bf(f - bf2f(h));
            gl += f;
            float w = waveReduceSum(f * fcnl);
            if (lane == 0) {
                ws[WS_RNORM + r] = sqrtf(s2);
                lp += fmaxf(w, 0.f); ln += fmaxf(-w, 0.f);
            }
        } else {
            Fh[r * 64 + lane] = 0;
            Fl[r * 64 + lane] = 0;
        }
    }
    atomicAdd(&gsh[lane], gl);
    if (lane == 0) { atomicAdd(&wsh2[0], lp); atomicAdd(&wsh2[1], ln); }
    __syncthreads();
    if (tid < 64) ws[WS_GPART + blockIdx.x * 64 + tid] = gsh[tid];
    if (tid == 64) ws[WS_WPART + blockIdx.x * 2 + 0] = wsh2[0];
    if (tid == 65) ws[WS_WPART + blockIdx.x * 2 + 1] = wsh2[1];
}

// K2: plain-bf16 MFMA gram, register-resident B (NO LDS -> no bank conflicts).
// grid (32,32), block 256, 64 v-rows/wave, B double-buffered in regs.
__global__ __launch_bounds__(256) void k_gram(
    const unsigned short* __restrict__ Fh, float* __restrict__ ws)
{
    int tid = threadIdx.x, lane = tid & 63, wid = tid >> 6;
    int m = lane & 15, quad = lane >> 4;
    int vbase = blockIdx.x * 256 + wid * 64;

    short8 AH[8];
#pragma unroll
    for (int pt = 0; pt < 4; pt++)
#pragma unroll
        for (int q = 0; q < 2; q++)
            AH[pt * 2 + q] = *(const short8*)(Fh + (vbase + pt * 16 + m) * 64 + q * 32 + quad * 8);

    float srr[16];
#pragma unroll
    for (int i = 0; i < 16; i++) srr[i] = 0.f;

    const int y = blockIdx.y;                 // u-tiles j = y + 32k, k=0..15
    const int boff = m * 64 + quad * 8;
    short8 B0[2], B1[2];
#pragma unroll
    for (int q = 0; q < 2; q++)
        B0[q] = *(const short8*)(Fh + y * 16 * 64 + boff + q * 32);

#pragma unroll 1
    for (int k2 = 0; k2 < 8; k2++) {
        int jB1 = y + 32 * (2 * k2 + 1);
#pragma unroll
        for (int q = 0; q < 2; q++)
            B1[q] = *(const short8*)(Fh + jB1 * 16 * 64 + boff + q * 32);
#pragma unroll
        for (int pt = 0; pt < 4; pt++) {
            f32x4 a = {0.f, 0.f, 0.f, 0.f};
            a = __builtin_amdgcn_mfma_f32_16x16x32_bf16(AH[pt * 2 + 0], B0[0], a, 0, 0, 0);
            a = __builtin_amdgcn_mfma_f32_16x16x32_bf16(AH[pt * 2 + 1], B0[1], a, 0, 0, 0);
#pragma unroll
            for (int r = 0; r < 4; r++) srr[pt * 4 + r] += fmaxf(a[r], 0.f);
        }
        if (k2 < 7) {
            int jB0 = y + 32 * (2 * k2 + 2);
#pragma unroll
            for (int q = 0; q < 2; q++)
                B0[q] = *(const short8*)(Fh + jB0 * 16 * 64 + boff + q * 32);
        }
#pragma unroll
        for (int pt = 0; pt < 4; pt++) {
            f32x4 a = {0.f, 0.f, 0.f, 0.f};
            a = __builtin_amdgcn_mfma_f32_16x16x32_bf16(AH[pt * 2 + 0], B1[0], a, 0, 0, 0);
            a = __builtin_amdgcn_mfma_f32_16x16x32_bf16(AH[pt * 2 + 1], B1[1], a, 0, 0, 0);
#pragma unroll
            for (int r = 0; r < 4; r++) srr[pt * 4 + r] += fmaxf(a[r], 0.f);
        }
    }
#pragma unroll
    for (int pt = 0; pt < 4; pt++)
#pragma unroll
        for (int r = 0; r < 4; r++) {
            float s = srr[pt * 4 + r];
            s += __shfl_xor(s, 1, 64); s += __shfl_xor(s, 2, 64);
            s += __shfl_xor(s, 4, 64); s += __shfl_xor(s, 8, 64);
            if (m == 0)
                ws[WS_SPART + y * 8192 + vbase + pt * 16 + quad * 4 + r] = s;
        }
}

// K3: FUSED e4 + sweep-0 mu update. 125x256.
__global__ __launch_bounds__(256) void k_mu0(
    const float* __restrict__ c, float* __restrict__ ws,
    unsigned short* __restrict__ MH, unsigned short* __restrict__ ML,
    const unsigned short* __restrict__ R2H, const unsigned short* __restrict__ R2L)
{
    __shared__ float XF[64][68];
    __shared__ float red[256], colp[256];
    __shared__ __align__(16) float wS[64], alS[64], beS[64], gaS[64], deS[64];
    __shared__ float fcnS[64], gS[64], sprow[64];
    __shared__ __align__(16) float e4sh[256];
    int tid = threadIdx.x, lane = tid & 63, wid = tid >> 6;
    int m = lane & 15, quad = lane >> 4;
    int v0 = blockIdx.x * 64;
    int cw = wid * 16 + m;
    int v = v0 + cw;

    if (wid == 0) {
        float cv = (lane < 63) ? c[lane] : 0.f;
        float cn2 = waveReduceSum(cv * cv);
        fcnS[lane] = cv * rsqrtf(cn2);
        wS[lane] = ws[WS_W + lane];
    } else if (wid == 1) {
        alS[lane] = ws[WS_AL + lane]; beS[lane] = ws[WS_BE + lane];
        float wp = 0.f;
#pragma unroll
        for (int k = 0; k < 8; k++) wp += ws[WS_WPART + (lane + 64 * k) * 2];
        wp = waveReduceSum(wp);
        if (lane == 0) ws[WS_WSUM] = wp;       // same value from every block
    } else if (wid == 2) {
        gaS[lane] = ws[WS_GA + lane]; deS[lane] = ws[WS_DE + lane];
        float wn = 0.f;
#pragma unroll
        for (int k = 0; k < 8; k++) wn += ws[WS_WPART + (lane + 64 * k) * 2 + 1];
        wn = waveReduceSum(wn);
        if (lane == 0) ws[WS_WSUM + 1] = wn;
    }
    float gv = 0.f;
#pragma unroll 8
    for (int bb = 0; bb < 128; bb++) gv += ws[WS_GPART + (wid * 128 + bb) * 64 + lane];
    red[tid] = gv;
    __syncthreads();
    if (tid < 64) gS[tid] = red[tid] + red[64 + tid] + red[128 + tid] + red[192 + tid];
    __syncthreads();
    float sv = 0.f;
#pragma unroll
    for (int y = wid * 8; y < wid * 8 + 8; y++) sv += ws[WS_SPART + y * 8192 + v0 + lane];
    red[tid] = sv;
    __syncthreads();
    if (tid < 64) sprow[tid] = red[tid] + red[64 + tid] + red[128 + tid] + red[192 + tid];
    __syncthreads();

    for (int i2 = 0; i2 < 16; i2++) {
        int i = wid * 16 + i2;
        int vr = v0 + i;
        float fr = bf2f(MH[vr * 64 + lane]) + bf2f(ML[vr * 64 + lane]);
        float dw = waveReduceSum(fr * fcnS[lane]);
        float dg = waveReduceSum(fr * gS[lane]);
        if (lane == 0) {
            float spv = sprow[i];
            float4 e;
            e.x = spv - 1.0f;          // remove diagonal relu(1)
            e.y = spv - dg;            // relu(-x) = relu(x) - x
            e.z = fmaxf(dw, 0.f);
            e.w = fmaxf(-dw, 0.f);
            *(float4*)(&e4sh[i * 4]) = e;
            *(float4*)(ws + WS_E4 + vr * 4) = e;   // for sweeps 1..4
        }
        XF[i][lane] = fr * ws[WS_RNORM + vr];       // mu0 row (fp32)
    }

    short8 RH[8], RL[8];
#pragma unroll
    for (int pt = 0; pt < 4; pt++)
#pragma unroll
        for (int q = 0; q < 2; q++) {
            int off = (pt * 16 + m) * 64 + q * 32 + quad * 8;
            RH[pt * 2 + q] = *(const short8*)(R2H + off);
            RL[pt * 2 + q] = *(const short8*)(R2L + off);
        }
    __syncthreads();

    short8 BH[2], BL[2];
#pragma unroll
    for (int q = 0; q < 2; q++) {
        float4 f0 = *(const float4*)(&XF[cw][q * 32 + quad * 8]);
        float4 f1 = *(const float4*)(&XF[cw][q * 32 + quad * 8 + 4]);
        float xv[8] = {f0.x, f0.y, f0.z, f0.w, f1.x, f1.y, f1.z, f1.w};
        short8 H, L;
#pragma unroll
        for (int j = 0; j < 8; j++) {
            unsigned short h = f2bf(xv[j]);
            H[j] = (short)h;
            L[j] = (short)f2bf(xv[j] - bf2f(h));
        }
        BH[q] = H; BL[q] = L;
    }
    float4 e = *(const float4*)(&e4sh[cw * 4]);

#pragma unroll
    for (int pt = 0; pt < 4; pt++) {
        f32x4 a = {0.f, 0.f, 0.f, 0.f};
#pragma unroll
        for (int q = 0; q < 2; q++) {
            a = __builtin_amdgcn_mfma_f32_16x16x32_bf16(RH[pt*2+q], BH[q], a, 0, 0, 0);
            a = __builtin_amdgcn_mfma_f32_16x16x32_bf16(RH[pt*2+q], BL[q], a, 0, 0, 0);
            a = __builtin_amdgcn_mfma_f32_16x16x32_bf16(RL[pt*2+q], BH[q], a, 0, 0, 0);
        }
        int pbase = pt * 16 + quad * 4;
        float4 w4 = *(const float4*)(wS + pbase);
        float4 a4 = *(const float4*)(alS + pbase);
        float4 b4 = *(const float4*)(beS + pbase);
        float4 g4 = *(const float4*)(gaS + pbase);
        float4 d4 = *(const float4*)(deS + pbase);
        float u0 = fmaxf(a[0] + w4.x + a4.x*e.x + b4.x*e.y + g4.x*e.z + d4.x*e.w, 0.f);
        float u1 = fmaxf(a[1] + w4.y + a4.y*e.x + b4.y*e.y + g4.y*e.z + d4.y*e.w, 0.f);
        float u2 = fmaxf(a[2] + w4.z + a4.z*e.x + b4.z*e.y + g4.z*e.z + d4.z*e.w, 0.f);
        float u3 = fmaxf(a[3] + w4.w + a4.w*e.x + b4.w*e.y + g4.w*e.z + d4.w*e.w, 0.f);
        ushort4 h4, l4;
        h4.x = f2bf(u0); l4.x = f2bf(u0 - bf2f(h4.x));
        h4.y = f2bf(u1); l4.y = f2bf(u1 - bf2f(h4.y));
        h4.z = f2bf(u2); l4.z = f2bf(u2 - bf2f(h4.z));
        h4.w = f2bf(u3); l4.w = f2bf(u3 - bf2f(h4.w));
        *(ushort4*)(MH + v * 64 + pbase) = h4;
        *(ushort4*)(ML + v * 64 + pbase) = l4;
        float c0 = u0, c1 = u1, c2 = u2, c3 = u3;
#pragma unroll
        for (int mm = 1; mm < 16; mm <<= 1) {
            c0 += __shfl_xor(c0, mm, 64);
            c1 += __shfl_xor(c1, mm, 64);
            c2 += __shfl_xor(c2, mm, 64);
            c3 += __shfl_xor(c3, mm, 64);
        }
        if (m == 0) {
            colp[wid * 64 + pbase + 0] = c0;
            colp[wid * 64 + pbase + 1] = c1;
            colp[wid * 64 + pbase + 2] = c2;
            colp[wid * 64 + pbase + 3] = c3;
        }
    }
    __syncthreads();
    if (tid < 64)
        ws[WS_CPART + blockIdx.x * 64 + tid] =
            colp[tid] + colp[64 + tid] + colp[128 + tid] + colp[192 + tid];
}

// K4: sweep t>=1 with colup(t-1) fused as redundant per-block prologue. 125x256.
__global__ __launch_bounds__(256) void k_mu(
    const float* __restrict__ th2cr, const float* __restrict__ th2rc,
    const int* __restrict__ zp, float* __restrict__ ws,
    unsigned short* __restrict__ MH, unsigned short* __restrict__ ML,
    const unsigned short* __restrict__ R2H, const unsigned short* __restrict__ R2L,
    int t)
{
    __shared__ float red[256], colp[256];
    __shared__ __align__(16) float wS[64], alS[64], beS[64], gaS[64], deS[64];
    __shared__ float Ssh[64], ysh[64];
    int tid = threadIdx.x, lane = tid & 63, wid = tid >> 6;
    int m = lane & 15, quad = lane >> 4;
    int v = (blockIdx.x * 4 + wid) * 16 + m;   // 125*4*16 = 8000
    int z = zp[0];

    if (tid < 64) {
        alS[tid] = ws[WS_AL + tid]; beS[tid] = ws[WS_BE + tid];
        gaS[tid] = ws[WS_GA + tid]; deS[tid] = ws[WS_DE + tid];
    }
    // ---- colup(t-1): S reduction + y + w (redundant per block)
    float s = 0.f;
    for (int blk = wid; blk < 125; blk += 4)
        s += ws[WS_CPART + (t - 1) * 8000 + blk * 64 + lane];
    red[tid] = s;
    __syncthreads();
    if (tid < 64) Ssh[tid] = red[tid] + red[64 + tid] + red[128 + tid] + red[192 + tid];
    __syncthreads();
    {
        int p = wid * 16 + m;
        float acc = 0.f;
        const float4* rowp = (const float4*)(th2cr + p * 64 + quad * 16);
#pragma unroll
        for (int kk = 0; kk < 4; kk++) {
            float4 r4 = rowp[kk];
            acc += r4.x * Ssh[quad * 16 + 4 * kk]     + r4.y * Ssh[quad * 16 + 4 * kk + 1]
                 + r4.z * Ssh[quad * 16 + 4 * kk + 2] + r4.w * Ssh[quad * 16 + 4 * kk + 3];
        }
        acc += __shfl_xor(acc, 16, 64);
        acc += __shfl_xor(acc, 32, 64);
        if (quad == 0)
            ysh[p] = fmaxf(acc + ws[WS_T1C + p] + ws[WS_WSUM] * ws[WS_ECP + p]
                           + ws[WS_WSUM + 1] * ws[WS_ECN + p], 0.f);
    }
    __syncthreads();
    {
        int p = wid * 16 + m;
        float acc = 0.f;
        const float4* rowp = (const float4*)(th2rc + p * 64 + quad * 16);
#pragma unroll
        for (int kk = 0; kk < 4; kk++) {
            float4 r4 = rowp[kk];
            acc += r4.x * ysh[quad * 16 + 4 * kk]     + r4.y * ysh[quad * 16 + 4 * kk + 1]
                 + r4.z * ysh[quad * 16 + 4 * kk + 2] + r4.w * ysh[quad * 16 + 4 * kk + 3];
        }
        acc += __shfl_xor(acc, 16, 64);
        acc += __shfl_xor(acc, 32, 64);
        if (quad == 0) wS[p] = acc + ws[WS_T1R + p];
    }

    // ---- mu update core
    short8 RH[8], RL[8];
#pragma unroll
    for (int pt = 0; pt < 4; pt++)
#pragma unroll
        for (int q = 0; q < 2; q++) {
            int off = (pt * 16 + m) * 64 + q * 32 + quad * 8;
            RH[pt * 2 + q] = *(const short8*)(R2H + off);
            RL[pt * 2 + q] = *(const short8*)(R2L + off);
        }
    short8 BH[2], BL[2];
#pragma unroll
    for (int q = 0; q < 2; q++) {
        BH[q] = *(const short8*)(MH + v * 64 + q * 32 + quad * 8);
        BL[q] = *(const short8*)(ML + v * 64 + q * 32 + quad * 8);
    }
    float4 e = *(const float4*)(ws + WS_E4 + v * 4);
    __syncthreads();

#pragma unroll
    for (int pt = 0; pt < 4; pt++) {
        f32x4 a = {0.f, 0.f, 0.f, 0.f};
#pragma unroll
        for (int q = 0; q < 2; q++) {
            a = __builtin_amdgcn_mfma_f32_16x16x32_bf16(RH[pt*2+q], BH[q], a, 0, 0, 0);
            a = __builtin_amdgcn_mfma_f32_16x16x32_bf16(RH[pt*2+q], BL[q], a, 0, 0, 0);
            a = __builtin_amdgcn_mfma_f32_16x16x32_bf16(RL[pt*2+q], BH[q], a, 0, 0, 0);
        }
        int pbase = pt * 16 + quad * 4;
        float4 w4 = *(const float4*)(wS + pbase);
        float4 a4 = *(const float4*)(alS + pbase);
        float4 b4 = *(const float4*)(beS + pbase);
        float4 g4 = *(const float4*)(gaS + pbase);
        float4 d4 = *(const float4*)(deS + pbase);
        float u0 = fmaxf(a[0] + w4.x + a4.x*e.x + b4.x*e.y + g4.x*e.z + d4.x*e.w, 0.f);
        float u1 = fmaxf(a[1] + w4.y + a4.y*e.x + b4.y*e.y + g4.y*e.z + d4.y*e.w, 0.f);
        float u2 = fmaxf(a[2] + w4.z + a4.z*e.x + b4.z*e.y + g4.z*e.z + d4.z*e.w, 0.f);
        float u3 = fmaxf(a[3] + w4.w + a4.w*e.x + b4.w*e.y + g4.w*e.z + d4.w*e.w, 0.f);
        ushort4 h4, l4;
        h4.x = f2bf(u0); l4.x = f2bf(u0 - bf2f(h4.x));
        h4.y = f2bf(u1); l4.y = f2bf(u1 - bf2f(h4.y));
        h4.z = f2bf(u2); l4.z = f2bf(u2 - bf2f(h4.z));
        h4.w = f2bf(u3); l4.w = f2bf(u3 - bf2f(h4.w));
        *(ushort4*)(MH + v * 64 + pbase) = h4;
        *(ushort4*)(ML + v * 64 + pbase) = l4;
        float c0 = u0, c1 = u1, c2 = u2, c3 = u3;
#pragma unroll
        for (int mm = 1; mm < 16; mm <<= 1) {
            c0 += __shfl_xor(c0, mm, 64);
            c1 += __shfl_xor(c1, mm, 64);
            c2 += __shfl_xor(c2, mm, 64);
            c3 += __shfl_xor(c3, mm, 64);
        }
        if (m == 0) {
            colp[wid * 64 + pbase + 0] = c0;
            colp[wid * 64 + pbase + 1] = c1;
            colp[wid * 64 + pbase + 2] = c2;
            colp[wid * 64 + pbase + 3] = c3;
        }
        if (t == 4 && v == z) {
            float4 o; o.x = u0; o.y = u1; o.z = u2; o.w = u3;
            *(float4*)(ws + WS_MUZ + pbase) = o;
        }
    }
    __syncthreads();
    if (tid < 64)
        ws[WS_CPART + t * 8000 + blockIdx.x * 64 + tid] =
            colp[tid] + colp[64 + tid] + colp[128 + tid] + colp[192 + tid];
}

// K5: final colup(4) + head. 1x256.
__global__ __launch_bounds__(256) void k_head(
    const float* __restrict__ th2cr,
    const float* __restrict__ th6r, const float* __restrict__ th6c,
    const float* __restrict__ th7, const float* __restrict__ W8,
    const float* __restrict__ b8,
    float* __restrict__ ws, float* __restrict__ out)
{
    __shared__ float red[256], Ssh[64], ysh[64], feat[128];
    int tid = threadIdx.x, lane = tid & 63, wid = tid >> 6;

    float s = 0.f;
    for (int blk = wid; blk < 125; blk += 4)
        s += ws[WS_CPART + 4 * 8000 + blk * 64 + lane];
    red[tid] = s;
    __syncthreads();
    if (tid < 64) Ssh[tid] = red[tid] + red[64 + tid] + red[128 + tid] + red[192 + tid];
    __syncthreads();
    int p = tid;
    if (p < 64) {
        float acc = ws[WS_T1C + p] + ws[WS_WSUM] * ws[WS_ECP + p]
                  + ws[WS_WSUM + 1] * ws[WS_ECN + p];
#pragma unroll 8
        for (int k = 0; k < 64; k++) acc += th2cr[p * 64 + k] * Ssh[k];
        ysh[p] = fmaxf(acc, 0.f);
    }
    __syncthreads();
    if (p < 64) {
        float t6 = 0.f, t7 = 0.f;
#pragma unroll 8
        for (int k = 0; k < 64; k++) {
            t6 += th6r[p * 64 + k] * Ssh[k] + th6c[p * 64 + k] * ysh[k];
            t7 += th7[p * 64 + k] * ws[WS_MUZ + k];
        }
        feat[p] = 1.f / (1.f + expf(-t6));
        feat[64 + p] = 1.f / (1.f + expf(-t7));
    }
    __syncthreads();
    if (p < 2) {
        float o = b8[p];
        for (int i = 0; i < 128; i++) o += W8[p * 128 + i] * feat[i];
        out[p] = o;
    }
}

extern "C" void kernel_launch(void* const* d_in, const int* in_sizes, int n_in,
                              void* d_out, int out_size, void* d_ws, size_t ws_size,
                              hipStream_t stream) {
    (void)in_sizes; (void)n_in; (void)out_size; (void)ws_size;
    const float* A     = (const float*)d_in[0];
    const float* b     = (const float*)d_in[1];
    const float* c     = (const float*)d_in[2];
    const float* th1r  = (const float*)d_in[3];
    const float* th1c  = (const float*)d_in[4];
    const float* th2rr = (const float*)d_in[5];
    const float* th2rc = (const float*)d_in[6];
    const float* th2cr = (const float*)d_in[7];
    const float* th3rr = (const float*)d_in[8];
    const float* th3rc = (const float*)d_in[9];
    const float* th3cr = (const float*)d_in[10];
    const float* th4rr = (const float*)d_in[11];
    const float* th4rc = (const float*)d_in[12];
    const float* th4cr = (const float*)d_in[13];
    const float* th6r  = (const float*)d_in[14];
    const float* th6c  = (const float*)d_in[15];
    const float* th7   = (const float*)d_in[16];
    const float* W8    = (const float*)d_in[17];
    const float* b8    = (const float*)d_in[18];
    const int*   zp    = (const int*)d_in[19];
    float* ws  = (float*)d_ws;
    float* out = (float*)d_out;
    unsigned short* Fh  = (unsigned short*)(ws + WS_FH);
    unsigned short* Fl  = (unsigned short*)(ws + WS_FL);
    unsigned short* R2H = (unsigned short*)(ws + WS_R2H);
    unsigned short* R2L = (unsigned short*)(ws + WS_R2L);

    k_fr<<<513, 256, 0, stream>>>(A, b, c, th1r, th1c, th2rr, th2rc, th3rr, th3rc,
                                  th3cr, th4rr, th4rc, th4cr, zp, Fh, Fl, R2H, R2L, ws);
    k_gram<<<dim3(32, 32), 256, 0, stream>>>(Fh, ws);
    k_mu0<<<125, 256, 0, stream>>>(c, ws, Fh, Fl, R2H, R2L);
    for (int t = 1; t < 5; t++)
        k_mu<<<125, 256, 0, stream>>>(th2cr, th2rc, zp, ws, Fh, Fl, R2H, R2L, t);
    k_head<<<1, 256, 0, stream>>>(th2cr, th6r, th6c, th7, W8, b8, ws, out);
}